// Round 1
// baseline (2245.446 us; speedup 1.0000x reference)
//
#include <hip/hip_runtime.h>
#include <math.h>

#define L_SEQ   1024
#define DMODEL  2048
#define DINNER  4096
#define DSTATE  16
#define DTRANK  128
#define N_XZ    (2 * DINNER)            // 8192
#define N_XP    (DTRANK + 2 * DSTATE)   // 160
#define EPS_F   1e-5f

__device__ __forceinline__ float silu_f(float v) {
    return v * (1.0f / (1.0f + __expf(-v)));
}
__device__ __forceinline__ float softplus_f(float v) {
    return (v > 15.0f) ? v : log1pf(__expf(v));
}

// ---------------- RMSNorm: one block per row ----------------
__global__ __launch_bounds__(256) void rmsnorm_kernel(const float* __restrict__ x,
                                                      const float* __restrict__ w,
                                                      float* __restrict__ xn) {
    const int row = blockIdx.x;
    const float4* xr = (const float4*)(x + (size_t)row * DMODEL);
    float ss = 0.f;
    float4 v0 = xr[threadIdx.x];
    float4 v1 = xr[threadIdx.x + 256];
    ss += v0.x*v0.x + v0.y*v0.y + v0.z*v0.z + v0.w*v0.w;
    ss += v1.x*v1.x + v1.y*v1.y + v1.z*v1.z + v1.w*v1.w;
    #pragma unroll
    for (int o = 32; o > 0; o >>= 1) ss += __shfl_down(ss, o);
    __shared__ float red[4];
    const int lane = threadIdx.x & 63, wv = threadIdx.x >> 6;
    if (lane == 0) red[wv] = ss;
    __syncthreads();
    if (threadIdx.x == 0) {
        float t = red[0] + red[1] + red[2] + red[3];
        red[0] = rsqrtf(t / (float)DMODEL + EPS_F);
    }
    __syncthreads();
    const float scale = red[0];
    const float4* wr = (const float4*)w;
    float4* outr = (float4*)(xn + (size_t)row * DMODEL);
    float4 w0 = wr[threadIdx.x];
    float4 w1 = wr[threadIdx.x + 256];
    float4 o0, o1;
    o0.x = v0.x * scale * w0.x; o0.y = v0.y * scale * w0.y;
    o0.z = v0.z * scale * w0.z; o0.w = v0.w * scale * w0.w;
    o1.x = v1.x * scale * w1.x; o1.y = v1.y * scale * w1.y;
    o1.z = v1.z * scale * w1.z; o1.w = v1.w * scale * w1.w;
    outr[threadIdx.x] = o0;
    outr[threadIdx.x + 256] = o1;
}

// ---------------- Depthwise causal conv (k=4) + SiLU ----------------
__global__ __launch_bounds__(256) void conv_silu_kernel(const float* __restrict__ xz,
                                                        const float* __restrict__ cw,
                                                        const float* __restrict__ cb,
                                                        float* __restrict__ xs) {
    const int idx = blockIdx.x * 256 + threadIdx.x;   // t * DINNER + c
    const int t = idx >> 12;
    const int c = idx & (DINNER - 1);
    float acc = cb[c];
    #pragma unroll
    for (int k = 0; k < 4; ++k) {
        const int tt = t + k - 3;
        if (tt >= 0) acc = fmaf(xz[(size_t)tt * N_XZ + c], cw[k * DINNER + c], acc);
    }
    xs[idx] = silu_f(acc);
}

// ---------------- fp32 tiled GEMM, 64x64 tile, 4x4 per thread ----------------
// MODE 0: C = A@B          MODE 1: C = softplus(A@B + bias[n])
// MODE 2: C = A@B + resid[m,n]
template <int MODE>
__global__ __launch_bounds__(256) void gemm_kernel(const float* __restrict__ A, int lda,
                                                   const float* __restrict__ B, int ldb,
                                                   float* __restrict__ C, int ldc,
                                                   int N, int K,
                                                   const float* __restrict__ bias,
                                                   const float* __restrict__ resid) {
    __shared__ float As[16][68];   // [k][m], +4 pad keeps float4 alignment, no conflicts
    __shared__ float Bs[16][64];   // [k][n]
    const int tid = threadIdx.x;
    const int tx = tid & 15, ty = tid >> 4;
    const int bm = blockIdx.y * 64, bn = blockIdx.x * 64;
    float acc[4][4] = {};
    const int ka = tid & 15, ma0 = tid >> 4;
    const int nb = tid & 63, kb0 = tid >> 6;

    for (int k0 = 0; k0 < K; k0 += 16) {
        #pragma unroll
        for (int i = 0; i < 4; ++i) {
            As[ka][ma0 + 16 * i] = A[(size_t)(bm + ma0 + 16 * i) * lda + k0 + ka];
        }
        #pragma unroll
        for (int i = 0; i < 4; ++i) {
            const int k = kb0 + 4 * i;
            float v = 0.f;
            if (bn + nb < N) v = B[(size_t)(k0 + k) * ldb + bn + nb];
            Bs[k][nb] = v;
        }
        __syncthreads();
        #pragma unroll
        for (int kk = 0; kk < 16; ++kk) {
            const float4 a4 = *(const float4*)&As[kk][ty * 4];
            const float4 b4 = *(const float4*)&Bs[kk][tx * 4];
            const float av[4] = {a4.x, a4.y, a4.z, a4.w};
            const float bv[4] = {b4.x, b4.y, b4.z, b4.w};
            #pragma unroll
            for (int i = 0; i < 4; ++i)
                #pragma unroll
                for (int j = 0; j < 4; ++j)
                    acc[i][j] = fmaf(av[i], bv[j], acc[i][j]);
        }
        __syncthreads();
    }

    #pragma unroll
    for (int i = 0; i < 4; ++i) {
        const int m = bm + ty * 4 + i;
        #pragma unroll
        for (int j = 0; j < 4; ++j) {
            const int n = bn + tx * 4 + j;
            if (n < N) {
                float v = acc[i][j];
                if (MODE == 1) v = softplus_f(v + bias[n]);
                if (MODE == 2) v += resid[(size_t)m * ldc + n];
                C[(size_t)m * ldc + n] = v;
            }
        }
    }
}

// ---------------- Selective scan: lane per (d, n), 16-lane reduce ----------------
// Gating with silu(res) fused into the write.
__global__ __launch_bounds__(256) void scan_kernel(const float* __restrict__ delta,
                                                   const float* __restrict__ xs,
                                                   const float* __restrict__ xdbc,
                                                   const float* __restrict__ xz,
                                                   const float* __restrict__ A_log,
                                                   const float* __restrict__ Dp,
                                                   float* __restrict__ yg) {
    const int n = threadIdx.x & 15;
    const int dg = threadIdx.x >> 4;
    const int d = blockIdx.x * 16 + dg;
    const float A = -__expf(A_log[d * DSTATE + n]);
    const float Dd = Dp[d];
    float h = 0.f;
    for (int t = 0; t < L_SEQ; ++t) {
        const float dl = delta[(size_t)t * DINNER + d];
        const float u  = xs[(size_t)t * DINNER + d];
        const float Bv = xdbc[t * N_XP + DTRANK + n];
        const float Cv = xdbc[t * N_XP + DTRANK + DSTATE + n];
        h = fmaf(h, __expf(dl * A), dl * Bv * u);
        float p = h * Cv;
        p += __shfl_xor(p, 1);
        p += __shfl_xor(p, 2);
        p += __shfl_xor(p, 4);
        p += __shfl_xor(p, 8);
        if (n == 0) {
            const float res = xz[(size_t)t * N_XZ + DINNER + d];
            yg[(size_t)t * DINNER + d] = (p + u * Dd) * silu_f(res);
        }
    }
}

extern "C" void kernel_launch(void* const* d_in, const int* in_sizes, int n_in,
                              void* d_out, int out_size, void* d_ws, size_t ws_size,
                              hipStream_t stream) {
    const float* x     = (const float*)d_in[0];
    const float* wn    = (const float*)d_in[1];
    const float* W_in  = (const float*)d_in[2];
    const float* cw    = (const float*)d_in[3];
    const float* cb    = (const float*)d_in[4];
    const float* W_xp  = (const float*)d_in[5];
    const float* W_dt  = (const float*)d_in[6];
    const float* b_dt  = (const float*)d_in[7];
    const float* A_log = (const float*)d_in[8];
    const float* Dp    = (const float*)d_in[9];
    const float* W_out = (const float*)d_in[10];
    float* out = (float*)d_out;

    float* ws    = (float*)d_ws;
    float* xn    = ws;                       // 1024*2048
    float* xz    = xn    + 2097152;          // 1024*8192
    float* xs    = xz    + 8388608;          // 1024*4096
    float* xdbc  = xs    + 4194304;          // 1024*160
    float* delta = xdbc  + 163840;           // 1024*4096
    float* yg    = delta + 4194304;          // 1024*4096  (total ~93 MB)

    // 1. RMSNorm
    rmsnorm_kernel<<<L_SEQ, 256, 0, stream>>>(x, wn, xn);
    // 2. xz = xn @ W_in   (1024 x 8192, K=2048)
    gemm_kernel<0><<<dim3(N_XZ / 64, L_SEQ / 64), 256, 0, stream>>>(
        xn, DMODEL, W_in, N_XZ, xz, N_XZ, N_XZ, DMODEL, nullptr, nullptr);
    // 3. xs = silu(causal_conv(xz[:, :4096]))
    conv_silu_kernel<<<(L_SEQ * DINNER) / 256, 256, 0, stream>>>(xz, cw, cb, xs);
    // 4. xdbc = xs @ W_xp  (1024 x 160, K=4096)
    gemm_kernel<0><<<dim3(3, L_SEQ / 64), 256, 0, stream>>>(
        xs, DINNER, W_xp, N_XP, xdbc, N_XP, N_XP, DINNER, nullptr, nullptr);
    // 5. delta = softplus(xdbc[:, :128] @ W_dt + b_dt)  (1024 x 4096, K=128)
    gemm_kernel<1><<<dim3(DINNER / 64, L_SEQ / 64), 256, 0, stream>>>(
        xdbc, N_XP, W_dt, DINNER, delta, DINNER, DINNER, DTRANK, b_dt, nullptr);
    // 6. selective scan + D-skip + gate  -> yg
    scan_kernel<<<DINNER / 16, 256, 0, stream>>>(delta, xs, xdbc, xz, A_log, Dp, yg);
    // 7. out = yg @ W_out + x  (1024 x 2048, K=4096)
    gemm_kernel<2><<<dim3(DMODEL / 64, L_SEQ / 64), 256, 0, stream>>>(
        yg, DINNER, W_out, DMODEL, out, DMODEL, DMODEL, DINNER, nullptr, x);
}

// Round 2
// 466.712 us; speedup vs baseline: 4.8112x; 4.8112x over previous
//
#include <hip/hip_runtime.h>
#include <math.h>

#define L_SEQ   1024
#define DMODEL  2048
#define DINNER  4096
#define DSTATE  16
#define DTRANK  128
#define N_XZ    (2 * DINNER)            // 8192
#define N_XP    (DTRANK + 2 * DSTATE)   // 160
#define EPS_F   1e-5f
#define NCHUNK  16
#define TCH     64

using bf16x8 = __attribute__((ext_vector_type(8))) short;
using f32x4  = __attribute__((ext_vector_type(4))) float;

__device__ __forceinline__ float silu_f(float v) {
    return v * (1.0f / (1.0f + __expf(-v)));
}
__device__ __forceinline__ float softplus_f(float v) {
    return (v > 15.0f) ? v : log1pf(__expf(v));
}
__device__ __forceinline__ unsigned short f2bf(float f) {
    unsigned b = __float_as_uint(f);
    return (unsigned short)((b + 0x7FFFu + ((b >> 16) & 1u)) >> 16);
}

#define GLOAD_LDS(gp, lp) \
    __builtin_amdgcn_global_load_lds((const __attribute__((address_space(1))) void*)(gp), \
                                     (__attribute__((address_space(3))) void*)(lp), 16, 0, 0)

// ---------------- fp32 W (K x N) -> bf16 W^T (N x K) ----------------
__global__ __launch_bounds__(256) void transpose_bf16_kernel(const float* __restrict__ W,
                                                             unsigned short* __restrict__ BT,
                                                             int K, int N) {
    __shared__ unsigned short Tl[32][33];
    const int k0 = blockIdx.y * 32, n0 = blockIdx.x * 32;
    const int r = threadIdx.x >> 3;
    const int c4 = (threadIdx.x & 7) * 4;
    float4 v = *(const float4*)&W[(size_t)(k0 + r) * N + n0 + c4];
    Tl[c4 + 0][r] = f2bf(v.x); Tl[c4 + 1][r] = f2bf(v.y);
    Tl[c4 + 2][r] = f2bf(v.z); Tl[c4 + 3][r] = f2bf(v.w);
    __syncthreads();
    const int c = threadIdx.x >> 3;
    const int r4 = (threadIdx.x & 7) * 4;
    ushort4 o;
    o.x = Tl[c][r4 + 0]; o.y = Tl[c][r4 + 1]; o.z = Tl[c][r4 + 2]; o.w = Tl[c][r4 + 3];
    *(ushort4*)&BT[(size_t)(n0 + c) * K + k0 + r4] = o;
}

// ---------------- RMSNorm -> bf16 ----------------
__global__ __launch_bounds__(256) void rmsnorm_kernel(const float* __restrict__ x,
                                                      const float* __restrict__ w,
                                                      unsigned short* __restrict__ xn) {
    const int row = blockIdx.x;
    const float4* xr = (const float4*)(x + (size_t)row * DMODEL);
    float ss = 0.f;
    float4 v0 = xr[threadIdx.x];
    float4 v1 = xr[threadIdx.x + 256];
    ss += v0.x*v0.x + v0.y*v0.y + v0.z*v0.z + v0.w*v0.w;
    ss += v1.x*v1.x + v1.y*v1.y + v1.z*v1.z + v1.w*v1.w;
    #pragma unroll
    for (int o = 32; o > 0; o >>= 1) ss += __shfl_down(ss, o);
    __shared__ float red[4];
    const int lane = threadIdx.x & 63, wv = threadIdx.x >> 6;
    if (lane == 0) red[wv] = ss;
    __syncthreads();
    if (threadIdx.x == 0) {
        float t = red[0] + red[1] + red[2] + red[3];
        red[0] = rsqrtf(t / (float)DMODEL + EPS_F);
    }
    __syncthreads();
    const float scale = red[0];
    const float4* wr = (const float4*)w;
    float4 w0 = wr[threadIdx.x];
    float4 w1 = wr[threadIdx.x + 256];
    ushort4 o0, o1;
    o0.x = f2bf(v0.x * scale * w0.x); o0.y = f2bf(v0.y * scale * w0.y);
    o0.z = f2bf(v0.z * scale * w0.z); o0.w = f2bf(v0.w * scale * w0.w);
    o1.x = f2bf(v1.x * scale * w1.x); o1.y = f2bf(v1.y * scale * w1.y);
    o1.z = f2bf(v1.z * scale * w1.z); o1.w = f2bf(v1.w * scale * w1.w);
    unsigned short* outr = xn + (size_t)row * DMODEL;
    *(ushort4*)&outr[threadIdx.x * 4] = o0;
    *(ushort4*)&outr[1024 + threadIdx.x * 4] = o1;
}

// ---------------- bf16 MFMA GEMM: C(MxN fp32) = A(MxK bf16) @ BT(NxK bf16)^T ----------------
// 4 waves in 2x2; wave tile (BM/2 x BN/2). MODE 0: plain. MODE 2: += resid.
template <int BM, int BN, int MODE>
__global__ __launch_bounds__(256) void gemm_mfma_kernel(const unsigned short* __restrict__ A,
                                                        const unsigned short* __restrict__ BT,
                                                        float* __restrict__ C,
                                                        int K, int ldc,
                                                        const float* __restrict__ resid) {
    constexpr int MT = BM / 32;   // 16x16 m-tiles per wave
    constexpr int NT = BN / 32;
    __shared__ __align__(16) unsigned short Al[BM * 32];
    __shared__ __align__(16) unsigned short Bl[BN * 32];
    const int tid = threadIdx.x;
    const int lane = tid & 63, wave = tid >> 6;
    const int wm = wave >> 1, wn = wave & 1;
    const int bm = blockIdx.y * BM, bn = blockIdx.x * BN;
    const int sr = lane >> 2;          // row within 16-row staging group
    const int sk = (lane & 3) * 8;     // k-element offset
    const int fr = lane & 15;          // fragment row/col
    const int fq = lane >> 4;          // quad

    f32x4 acc[MT][NT];
    #pragma unroll
    for (int i = 0; i < MT; ++i)
        #pragma unroll
        for (int j = 0; j < NT; ++j)
            acc[i][j] = (f32x4){0.f, 0.f, 0.f, 0.f};

    for (int k0 = 0; k0 < K; k0 += 32) {
        #pragma unroll
        for (int is = wave; is < BM / 16; is += 4)
            GLOAD_LDS(&A[(size_t)(bm + is * 16 + sr) * K + k0 + sk], &Al[is * 512]);
        #pragma unroll
        for (int is = wave; is < BN / 16; is += 4)
            GLOAD_LDS(&BT[(size_t)(bn + is * 16 + sr) * K + k0 + sk], &Bl[is * 512]);
        __syncthreads();
        bf16x8 af[MT], bfr[NT];
        #pragma unroll
        for (int i = 0; i < MT; ++i)
            af[i] = *(const bf16x8*)&Al[(wm * (BM / 2) + i * 16 + fr) * 32 + fq * 8];
        #pragma unroll
        for (int j = 0; j < NT; ++j)
            bfr[j] = *(const bf16x8*)&Bl[(wn * (BN / 2) + j * 16 + fr) * 32 + fq * 8];
        #pragma unroll
        for (int i = 0; i < MT; ++i)
            #pragma unroll
            for (int j = 0; j < NT; ++j)
                acc[i][j] = __builtin_amdgcn_mfma_f32_16x16x32_bf16(af[i], bfr[j], acc[i][j], 0, 0, 0);
        __syncthreads();
    }

    #pragma unroll
    for (int i = 0; i < MT; ++i) {
        const int row = bm + wm * (BM / 2) + i * 16 + fq * 4;
        #pragma unroll
        for (int j = 0; j < NT; ++j) {
            const int col = bn + wn * (BN / 2) + j * 16 + fr;
            #pragma unroll
            for (int r = 0; r < 4; ++r) {
                float v = acc[i][j][r];
                if (MODE == 2) v += resid[(size_t)(row + r) * ldc + col];
                C[(size_t)(row + r) * ldc + col] = v;
            }
        }
    }
}

// ---------------- Depthwise causal conv (k=4) + SiLU ----------------
__global__ __launch_bounds__(256) void conv_silu_kernel(const float* __restrict__ xz,
                                                        const float* __restrict__ cw,
                                                        const float* __restrict__ cb,
                                                        float* __restrict__ xs) {
    const int idx = blockIdx.x * 256 + threadIdx.x;
    const int t = idx >> 12;
    const int c = idx & (DINNER - 1);
    float acc = cb[c];
    #pragma unroll
    for (int k = 0; k < 4; ++k) {
        const int tt = t + k - 3;
        if (tt >= 0) acc = fmaf(xz[(size_t)tt * N_XZ + c], cw[k * DINNER + c], acc);
    }
    xs[idx] = silu_f(acc);
}

// ---------------- fp32 tiled GEMM (64x64), optional K-split via blockIdx.z ----------------
// MODE 0: C = A@B   MODE 1: C = softplus(A@B + bias[n])
template <int MODE>
__global__ __launch_bounds__(256) void gemm_kernel(const float* __restrict__ A, int lda,
                                                   const float* __restrict__ B, int ldb,
                                                   float* __restrict__ C, int ldc,
                                                   int N, int Kc,
                                                   size_t zAoff, size_t zBoff, size_t zCoff,
                                                   const float* __restrict__ bias) {
    A += (size_t)blockIdx.z * zAoff;
    B += (size_t)blockIdx.z * zBoff;
    C += (size_t)blockIdx.z * zCoff;
    __shared__ float As[16][68];
    __shared__ float Bs[16][64];
    const int tid = threadIdx.x;
    const int tx = tid & 15, ty = tid >> 4;
    const int bm = blockIdx.y * 64, bn = blockIdx.x * 64;
    float acc[4][4] = {};
    const int ka = tid & 15, ma0 = tid >> 4;
    const int nb = tid & 63, kb0 = tid >> 6;

    for (int k0 = 0; k0 < Kc; k0 += 16) {
        #pragma unroll
        for (int i = 0; i < 4; ++i) {
            As[ka][ma0 + 16 * i] = A[(size_t)(bm + ma0 + 16 * i) * lda + k0 + ka];
        }
        #pragma unroll
        for (int i = 0; i < 4; ++i) {
            const int k = kb0 + 4 * i;
            float v = 0.f;
            if (bn + nb < N) v = B[(size_t)(k0 + k) * ldb + bn + nb];
            Bs[k][nb] = v;
        }
        __syncthreads();
        #pragma unroll
        for (int kk = 0; kk < 16; ++kk) {
            const float4 a4 = *(const float4*)&As[kk][ty * 4];
            const float4 b4 = *(const float4*)&Bs[kk][tx * 4];
            const float av[4] = {a4.x, a4.y, a4.z, a4.w};
            const float bv[4] = {b4.x, b4.y, b4.z, b4.w};
            #pragma unroll
            for (int i = 0; i < 4; ++i)
                #pragma unroll
                for (int j = 0; j < 4; ++j)
                    acc[i][j] = fmaf(av[i], bv[j], acc[i][j]);
        }
        __syncthreads();
    }

    #pragma unroll
    for (int i = 0; i < 4; ++i) {
        const int m = bm + ty * 4 + i;
        #pragma unroll
        for (int j = 0; j < 4; ++j) {
            const int n = bn + tx * 4 + j;
            if (n < N) {
                float v = acc[i][j];
                if (MODE == 1) v = softplus_f(v + bias[n]);
                C[(size_t)m * ldc + n] = v;
            }
        }
    }
}

__global__ __launch_bounds__(256) void reduce8_kernel(const float* __restrict__ part,
                                                      float* __restrict__ out) {
    const int i = blockIdx.x * 256 + threadIdx.x;
    float s = 0.f;
    #pragma unroll
    for (int c = 0; c < 8; ++c) s += part[(size_t)c * (L_SEQ * N_XP) + i];
    out[i] = s;
}

// ---------------- Selective scan, 3-pass chunked linear recurrence ----------------
// Pass 1: per (chunk, d): local scan h (h0=0), store final h (S) and sum(delta).
__global__ __launch_bounds__(256) void scan_pass1(const float* __restrict__ delta,
                                                  const float* __restrict__ xs,
                                                  const float* __restrict__ xdbc,
                                                  const float* __restrict__ A_log,
                                                  float* __restrict__ S,
                                                  float* __restrict__ sumdl) {
    __shared__ float BC[TCH][32];
    const int c = blockIdx.y;
    const int d = blockIdx.x * 256 + threadIdx.x;
    const int t0 = c * TCH;
    {
        const int tt = threadIdx.x >> 2, q = threadIdx.x & 3;
        float4 v0 = *(const float4*)&xdbc[(size_t)(t0 + tt) * N_XP + DTRANK + q * 8];
        float4 v1 = *(const float4*)&xdbc[(size_t)(t0 + tt) * N_XP + DTRANK + q * 8 + 4];
        *(float4*)&BC[tt][q * 8] = v0;
        *(float4*)&BC[tt][q * 8 + 4] = v1;
    }
    __syncthreads();
    float Aa[16];
    #pragma unroll
    for (int n = 0; n < 16; ++n) Aa[n] = -__expf(A_log[d * 16 + n]);
    float h[16];
    #pragma unroll
    for (int n = 0; n < 16; ++n) h[n] = 0.f;
    float sd = 0.f;
    for (int t = 0; t < TCH; ++t) {
        const float dl = delta[(size_t)(t0 + t) * DINNER + d];
        const float u  = xs[(size_t)(t0 + t) * DINNER + d];
        sd += dl;
        const float du = dl * u;
        #pragma unroll
        for (int n = 0; n < 16; ++n)
            h[n] = fmaf(h[n], __expf(dl * Aa[n]), du * BC[t][n]);
    }
    float* Sp = &S[((size_t)c * DINNER + d) * 16];
    #pragma unroll
    for (int n = 0; n < 16; n += 4)
        *(float4*)&Sp[n] = make_float4(h[n], h[n + 1], h[n + 2], h[n + 3]);
    sumdl[c * DINNER + d] = sd;
}

// Pass 2: per (d, n): stitch chunk boundaries -> exclusive initial state h0 per chunk.
__global__ __launch_bounds__(256) void scan_pass2(const float* __restrict__ S,
                                                  const float* __restrict__ sumdl,
                                                  const float* __restrict__ A_log,
                                                  float* __restrict__ h0) {
    const int i = blockIdx.x * 256 + threadIdx.x;   // d*16 + n
    const int dd = i >> 4;
    const float A = -__expf(A_log[i]);
    float h = 0.f;
    #pragma unroll
    for (int c = 0; c < NCHUNK; ++c) {
        h0[(size_t)c * (DINNER * 16) + i] = h;
        h = h * __expf(A * sumdl[c * DINNER + dd]) + S[(size_t)c * (DINNER * 16) + i];
    }
}

// Pass 3: rescan with true h0, emit gated bf16 output.
__global__ __launch_bounds__(256) void scan_pass3(const float* __restrict__ delta,
                                                  const float* __restrict__ xs,
                                                  const float* __restrict__ xdbc,
                                                  const float* __restrict__ xz,
                                                  const float* __restrict__ A_log,
                                                  const float* __restrict__ Dp,
                                                  const float* __restrict__ h0,
                                                  unsigned short* __restrict__ yg_bf) {
    __shared__ float BC[TCH][32];
    const int c = blockIdx.y;
    const int d = blockIdx.x * 256 + threadIdx.x;
    const int t0 = c * TCH;
    {
        const int tt = threadIdx.x >> 2, q = threadIdx.x & 3;
        float4 v0 = *(const float4*)&xdbc[(size_t)(t0 + tt) * N_XP + DTRANK + q * 8];
        float4 v1 = *(const float4*)&xdbc[(size_t)(t0 + tt) * N_XP + DTRANK + q * 8 + 4];
        *(float4*)&BC[tt][q * 8] = v0;
        *(float4*)&BC[tt][q * 8 + 4] = v1;
    }
    __syncthreads();
    float Aa[16];
    #pragma unroll
    for (int n = 0; n < 16; ++n) Aa[n] = -__expf(A_log[d * 16 + n]);
    float h[16];
    const float* h0p = &h0[(size_t)c * (DINNER * 16) + d * 16];
    #pragma unroll
    for (int n = 0; n < 16; n += 4) {
        float4 v = *(const float4*)&h0p[n];
        h[n] = v.x; h[n + 1] = v.y; h[n + 2] = v.z; h[n + 3] = v.w;
    }
    const float Dd = Dp[d];
    for (int t = 0; t < TCH; ++t) {
        const float dl = delta[(size_t)(t0 + t) * DINNER + d];
        const float u  = xs[(size_t)(t0 + t) * DINNER + d];
        const float du = dl * u;
        float y = 0.f;
        #pragma unroll
        for (int n = 0; n < 16; ++n) {
            h[n] = fmaf(h[n], __expf(dl * Aa[n]), du * BC[t][n]);
            y = fmaf(h[n], BC[t][16 + n], y);
        }
        const float res = xz[(size_t)(t0 + t) * N_XZ + DINNER + d];
        yg_bf[(size_t)(t0 + t) * DINNER + d] = f2bf((y + u * Dd) * silu_f(res));
    }
}

extern "C" void kernel_launch(void* const* d_in, const int* in_sizes, int n_in,
                              void* d_out, int out_size, void* d_ws, size_t ws_size,
                              hipStream_t stream) {
    const float* x     = (const float*)d_in[0];
    const float* wn    = (const float*)d_in[1];
    const float* W_in  = (const float*)d_in[2];
    const float* cw    = (const float*)d_in[3];
    const float* cb    = (const float*)d_in[4];
    const float* W_xp  = (const float*)d_in[5];
    const float* W_dt  = (const float*)d_in[6];
    const float* b_dt  = (const float*)d_in[7];
    const float* A_log = (const float*)d_in[8];
    const float* Dp    = (const float*)d_in[9];
    const float* W_out = (const float*)d_in[10];
    float* out = (float*)d_out;

    float* ws = (float*)d_ws;
    float*          xz    = ws;                                   //  8,388,608 f
    float*          xs    = xz + 8388608;                         //  4,194,304 f
    float*          delta = xs + 4194304;                         //  4,194,304 f
    float*          xdbc  = delta + 4194304;                      //    163,840 f
    unsigned short* xn_bf = (unsigned short*)(xdbc + 163840);     //  2,097,152 bf16
    unsigned short* yg_bf = xn_bf + 2097152;                      //  4,194,304 bf16
    unsigned short* BT    = yg_bf + 4194304;                      // 16,777,216 bf16 (33.5 MB, reused)
    // Aliases inside the BT region (live only while BT_in is dead):
    float* part  = (float*)BT;            // 8 * 1024*160 = 1,310,720 f
    float* S     = part + 1310720;        // 1,048,576 f
    float* sumdl = S + 1048576;           //    65,536 f
    float* h0    = sumdl + 65536;         // 1,048,576 f
    // total ws use: ~114 MB

    // 1. W_in (2048x8192) -> BT bf16 (8192x2048)
    transpose_bf16_kernel<<<dim3(N_XZ / 32, DMODEL / 32), 256, 0, stream>>>(W_in, BT, DMODEL, N_XZ);
    // 2. RMSNorm -> bf16
    rmsnorm_kernel<<<L_SEQ, 256, 0, stream>>>(x, wn, xn_bf);
    // 3. xz = xn @ W_in  (MFMA, 1024x8192, K=2048)
    gemm_mfma_kernel<128, 128, 0><<<dim3(N_XZ / 128, L_SEQ / 128), 256, 0, stream>>>(
        xn_bf, BT, xz, DMODEL, N_XZ, nullptr);
    // 4. conv + silu
    conv_silu_kernel<<<(L_SEQ * DINNER) / 256, 256, 0, stream>>>(xz, cw, cb, xs);
    // 5. xdbc = xs @ W_xp  (split-K x8, fp32)
    gemm_kernel<0><<<dim3(3, L_SEQ / 64, 8), 256, 0, stream>>>(
        xs, DINNER, W_xp, N_XP, part, N_XP, N_XP, DINNER / 8,
        (size_t)(DINNER / 8), (size_t)(DINNER / 8) * N_XP, (size_t)L_SEQ * N_XP, nullptr);
    reduce8_kernel<<<(L_SEQ * N_XP) / 256, 256, 0, stream>>>(part, xdbc);
    // 6. delta = softplus(xdbc[:, :128] @ W_dt + b_dt)  (fp32, K=128)
    gemm_kernel<1><<<dim3(DINNER / 64, L_SEQ / 64, 1), 256, 0, stream>>>(
        xdbc, N_XP, W_dt, DINNER, delta, DINNER, DINNER, DTRANK, 0, 0, 0, b_dt);
    // 7. selective scan (3 passes) + gate -> yg bf16
    scan_pass1<<<dim3(DINNER / 256, NCHUNK), 256, 0, stream>>>(delta, xs, xdbc, A_log, S, sumdl);
    scan_pass2<<<(DINNER * 16) / 256, 256, 0, stream>>>(S, sumdl, A_log, h0);
    scan_pass3<<<dim3(DINNER / 256, NCHUNK), 256, 0, stream>>>(delta, xs, xdbc, xz, A_log, Dp, h0, yg_bf);
    // 8. W_out (4096x2048) -> BT bf16 (2048x4096)   (scan scratch now dead)
    transpose_bf16_kernel<<<dim3(DMODEL / 32, DINNER / 32), 256, 0, stream>>>(W_out, BT, DINNER, DMODEL);
    // 9. out = yg @ W_out + x  (MFMA, 1024x2048, K=4096)
    gemm_mfma_kernel<64, 128, 2><<<dim3(DMODEL / 128, L_SEQ / 64), 256, 0, stream>>>(
        yg_bf, BT, out, DINNER, DMODEL, x);
}

// Round 3
// 421.046 us; speedup vs baseline: 5.3330x; 1.1085x over previous
//
#include <hip/hip_runtime.h>
#include <math.h>

#define L_SEQ   1024
#define DMODEL  2048
#define DINNER  4096
#define DSTATE  16
#define DTRANK  128
#define N_XZ    (2 * DINNER)            // 8192
#define N_XP    (DTRANK + 2 * DSTATE)   // 160
#define EPS_F   1e-5f
#define NCHUNK  16
#define TCH     64
#define SK_XP   16                      // split-K factor for xdbc GEMM

using bf16x8 = __attribute__((ext_vector_type(8))) short;
using f32x4  = __attribute__((ext_vector_type(4))) float;

__device__ __forceinline__ float silu_f(float v) {
    return v * (1.0f / (1.0f + __expf(-v)));
}
__device__ __forceinline__ float softplus_f(float v) {
    return (v > 15.0f) ? v : log1pf(__expf(v));
}
__device__ __forceinline__ unsigned short f2bf(float f) {
    unsigned b = __float_as_uint(f);
    return (unsigned short)((b + 0x7FFFu + ((b >> 16) & 1u)) >> 16);
}

#define GLOAD_LDS(gp, lp) \
    __builtin_amdgcn_global_load_lds((const __attribute__((address_space(1))) void*)(gp), \
                                     (__attribute__((address_space(3))) void*)(lp), 16, 0, 0)

// ---------------- fp32 W (K x N) -> bf16 W^T (N x K) ----------------
__global__ __launch_bounds__(256) void transpose_bf16_kernel(const float* __restrict__ W,
                                                             unsigned short* __restrict__ BT,
                                                             int K, int N) {
    __shared__ unsigned short Tl[32][33];
    const int k0 = blockIdx.y * 32, n0 = blockIdx.x * 32;
    const int r = threadIdx.x >> 3;
    const int c4 = (threadIdx.x & 7) * 4;
    float4 v = *(const float4*)&W[(size_t)(k0 + r) * N + n0 + c4];
    Tl[c4 + 0][r] = f2bf(v.x); Tl[c4 + 1][r] = f2bf(v.y);
    Tl[c4 + 2][r] = f2bf(v.z); Tl[c4 + 3][r] = f2bf(v.w);
    __syncthreads();
    const int c = threadIdx.x >> 3;
    const int r4 = (threadIdx.x & 7) * 4;
    ushort4 o;
    o.x = Tl[c][r4 + 0]; o.y = Tl[c][r4 + 1]; o.z = Tl[c][r4 + 2]; o.w = Tl[c][r4 + 3];
    *(ushort4*)&BT[(size_t)(n0 + c) * K + k0 + r4] = o;
}

// ---------------- RMSNorm -> bf16 ----------------
__global__ __launch_bounds__(256) void rmsnorm_kernel(const float* __restrict__ x,
                                                      const float* __restrict__ w,
                                                      unsigned short* __restrict__ xn) {
    const int row = blockIdx.x;
    const float4* xr = (const float4*)(x + (size_t)row * DMODEL);
    float ss = 0.f;
    float4 v0 = xr[threadIdx.x];
    float4 v1 = xr[threadIdx.x + 256];
    ss += v0.x*v0.x + v0.y*v0.y + v0.z*v0.z + v0.w*v0.w;
    ss += v1.x*v1.x + v1.y*v1.y + v1.z*v1.z + v1.w*v1.w;
    #pragma unroll
    for (int o = 32; o > 0; o >>= 1) ss += __shfl_down(ss, o);
    __shared__ float red[4];
    const int lane = threadIdx.x & 63, wv = threadIdx.x >> 6;
    if (lane == 0) red[wv] = ss;
    __syncthreads();
    if (threadIdx.x == 0) {
        float t = red[0] + red[1] + red[2] + red[3];
        red[0] = rsqrtf(t / (float)DMODEL + EPS_F);
    }
    __syncthreads();
    const float scale = red[0];
    const float4* wr = (const float4*)w;
    float4 w0 = wr[threadIdx.x];
    float4 w1 = wr[threadIdx.x + 256];
    ushort4 o0, o1;
    o0.x = f2bf(v0.x * scale * w0.x); o0.y = f2bf(v0.y * scale * w0.y);
    o0.z = f2bf(v0.z * scale * w0.z); o0.w = f2bf(v0.w * scale * w0.w);
    o1.x = f2bf(v1.x * scale * w1.x); o1.y = f2bf(v1.y * scale * w1.y);
    o1.z = f2bf(v1.z * scale * w1.z); o1.w = f2bf(v1.w * scale * w1.w);
    unsigned short* outr = xn + (size_t)row * DMODEL;
    *(ushort4*)&outr[threadIdx.x * 4] = o0;
    *(ushort4*)&outr[1024 + threadIdx.x * 4] = o1;
}

// ---------------- bf16 MFMA GEMM: C(MxN fp32) = A(MxK bf16) @ BT(NxK bf16)^T ----------------
// 4 waves 2x2; wave tile (BM/2 x BN/2).
// MODE 0: plain (also split-K partial via blockIdx.z)
// MODE 1: softplus(v + bias[col])    MODE 2: v + resid[row,col]
template <int BM, int BN, int MODE>
__global__ __launch_bounds__(256) void gemm_mfma_kernel(const unsigned short* __restrict__ A,
                                                        const unsigned short* __restrict__ BT,
                                                        float* __restrict__ C,
                                                        int K, int Kc, int ldc, int Ncols,
                                                        const float* __restrict__ bias,
                                                        const float* __restrict__ resid) {
    constexpr int MT = BM / 32;
    constexpr int NT = BN / 32;
    __shared__ __align__(16) unsigned short Al[BM * 32];
    __shared__ __align__(16) unsigned short Bl[BN * 32];
    const int tid = threadIdx.x;
    const int lane = tid & 63, wave = tid >> 6;
    const int wm = wave >> 1, wn = wave & 1;
    const int bm = blockIdx.y * BM, bn = blockIdx.x * BN;
    const size_t koff = (size_t)blockIdx.z * Kc;
    C += (size_t)blockIdx.z * (size_t)gridDim.y * BM * ldc;
    const int sr = lane >> 2;
    const int sk = (lane & 3) * 8;
    const int fr = lane & 15;
    const int fq = lane >> 4;

    f32x4 acc[MT][NT];
    #pragma unroll
    for (int i = 0; i < MT; ++i)
        #pragma unroll
        for (int j = 0; j < NT; ++j)
            acc[i][j] = (f32x4){0.f, 0.f, 0.f, 0.f};

    for (int k0 = 0; k0 < Kc; k0 += 32) {
        #pragma unroll
        for (int is = wave; is < BM / 16; is += 4)
            GLOAD_LDS(&A[(size_t)(bm + is * 16 + sr) * K + koff + k0 + sk], &Al[is * 512]);
        #pragma unroll
        for (int is = wave; is < BN / 16; is += 4)
            GLOAD_LDS(&BT[(size_t)(bn + is * 16 + sr) * K + koff + k0 + sk], &Bl[is * 512]);
        __syncthreads();
        bf16x8 af[MT], bfr[NT];
        #pragma unroll
        for (int i = 0; i < MT; ++i)
            af[i] = *(const bf16x8*)&Al[(wm * (BM / 2) + i * 16 + fr) * 32 + fq * 8];
        #pragma unroll
        for (int j = 0; j < NT; ++j)
            bfr[j] = *(const bf16x8*)&Bl[(wn * (BN / 2) + j * 16 + fr) * 32 + fq * 8];
        #pragma unroll
        for (int i = 0; i < MT; ++i)
            #pragma unroll
            for (int j = 0; j < NT; ++j)
                acc[i][j] = __builtin_amdgcn_mfma_f32_16x16x32_bf16(af[i], bfr[j], acc[i][j], 0, 0, 0);
        __syncthreads();
    }

    #pragma unroll
    for (int i = 0; i < MT; ++i) {
        const int row = bm + wm * (BM / 2) + i * 16 + fq * 4;
        #pragma unroll
        for (int j = 0; j < NT; ++j) {
            const int col = bn + wn * (BN / 2) + j * 16 + fr;
            if (col < Ncols) {
                #pragma unroll
                for (int r = 0; r < 4; ++r) {
                    float v = acc[i][j][r];
                    if (MODE == 1) v = softplus_f(v + bias[col]);
                    if (MODE == 2) v += resid[(size_t)(row + r) * ldc + col];
                    C[(size_t)(row + r) * ldc + col] = v;
                }
            }
        }
    }
}

// ---------------- Depthwise causal conv (k=4) + SiLU; fp32 + bf16 outputs ----------------
__global__ __launch_bounds__(256) void conv_silu_kernel(const float* __restrict__ xz,
                                                        const float* __restrict__ cw,
                                                        const float* __restrict__ cb,
                                                        float* __restrict__ xs,
                                                        unsigned short* __restrict__ xs_bf) {
    const int idx = blockIdx.x * 256 + threadIdx.x;
    const int t = idx >> 12;
    const int c = idx & (DINNER - 1);
    float acc = cb[c];
    #pragma unroll
    for (int k = 0; k < 4; ++k) {
        const int tt = t + k - 3;
        if (tt >= 0) acc = fmaf(xz[(size_t)tt * N_XZ + c], cw[k * DINNER + c], acc);
    }
    const float s = silu_f(acc);
    xs[idx] = s;
    xs_bf[idx] = f2bf(s);
}

// ---------------- reduce SK_XP split-K partials -> xdbc fp32 (+ bf16 dt cols) ----------------
__global__ __launch_bounds__(256) void reduce_sk_kernel(const float* __restrict__ part,
                                                        float* __restrict__ xdbc,
                                                        unsigned short* __restrict__ xdbc_dt) {
    const int i = blockIdx.x * 256 + threadIdx.x;     // row*160 + col
    float s = 0.f;
    #pragma unroll
    for (int c = 0; c < SK_XP; ++c) s += part[(size_t)c * (L_SEQ * N_XP) + i];
    xdbc[i] = s;
    const int col = i % N_XP;
    if (col < DTRANK) xdbc_dt[(i / N_XP) * DTRANK + col] = f2bf(s);
}

// ---------------- Selective scan, 3-pass chunked linear recurrence ----------------
__global__ __launch_bounds__(256) void scan_pass1(const float* __restrict__ delta,
                                                  const float* __restrict__ xs,
                                                  const float* __restrict__ xdbc,
                                                  const float* __restrict__ A_log,
                                                  float* __restrict__ S,
                                                  float* __restrict__ sumdl) {
    __shared__ float BC[TCH][32];
    const int c = blockIdx.y;
    const int d = blockIdx.x * 256 + threadIdx.x;
    const int t0 = c * TCH;
    {
        const int tt = threadIdx.x >> 2, q = threadIdx.x & 3;
        float4 v0 = *(const float4*)&xdbc[(size_t)(t0 + tt) * N_XP + DTRANK + q * 8];
        float4 v1 = *(const float4*)&xdbc[(size_t)(t0 + tt) * N_XP + DTRANK + q * 8 + 4];
        *(float4*)&BC[tt][q * 8] = v0;
        *(float4*)&BC[tt][q * 8 + 4] = v1;
    }
    __syncthreads();
    float Aa[16];
    #pragma unroll
    for (int n = 0; n < 16; ++n) Aa[n] = -__expf(A_log[d * 16 + n]);
    float h[16];
    #pragma unroll
    for (int n = 0; n < 16; ++n) h[n] = 0.f;
    float sd = 0.f;
    for (int t = 0; t < TCH; ++t) {
        const float dl = delta[(size_t)(t0 + t) * DINNER + d];
        const float u  = xs[(size_t)(t0 + t) * DINNER + d];
        sd += dl;
        const float du = dl * u;
        #pragma unroll
        for (int n = 0; n < 16; ++n)
            h[n] = fmaf(h[n], __expf(dl * Aa[n]), du * BC[t][n]);
    }
    float* Sp = &S[((size_t)c * DINNER + d) * 16];
    #pragma unroll
    for (int n = 0; n < 16; n += 4)
        *(float4*)&Sp[n] = make_float4(h[n], h[n + 1], h[n + 2], h[n + 3]);
    sumdl[c * DINNER + d] = sd;
}

__global__ __launch_bounds__(256) void scan_pass2(const float* __restrict__ S,
                                                  const float* __restrict__ sumdl,
                                                  const float* __restrict__ A_log,
                                                  float* __restrict__ h0) {
    const int i = blockIdx.x * 256 + threadIdx.x;   // d*16 + n
    const int dd = i >> 4;
    const float A = -__expf(A_log[i]);
    float h = 0.f;
    #pragma unroll
    for (int c = 0; c < NCHUNK; ++c) {
        h0[(size_t)c * (DINNER * 16) + i] = h;
        h = h * __expf(A * sumdl[c * DINNER + dd]) + S[(size_t)c * (DINNER * 16) + i];
    }
}

__global__ __launch_bounds__(256) void scan_pass3(const float* __restrict__ delta,
                                                  const float* __restrict__ xs,
                                                  const float* __restrict__ xdbc,
                                                  const float* __restrict__ xz,
                                                  const float* __restrict__ A_log,
                                                  const float* __restrict__ Dp,
                                                  const float* __restrict__ h0,
                                                  unsigned short* __restrict__ yg_bf) {
    __shared__ float BC[TCH][32];
    const int c = blockIdx.y;
    const int d = blockIdx.x * 256 + threadIdx.x;
    const int t0 = c * TCH;
    {
        const int tt = threadIdx.x >> 2, q = threadIdx.x & 3;
        float4 v0 = *(const float4*)&xdbc[(size_t)(t0 + tt) * N_XP + DTRANK + q * 8];
        float4 v1 = *(const float4*)&xdbc[(size_t)(t0 + tt) * N_XP + DTRANK + q * 8 + 4];
        *(float4*)&BC[tt][q * 8] = v0;
        *(float4*)&BC[tt][q * 8 + 4] = v1;
    }
    __syncthreads();
    float Aa[16];
    #pragma unroll
    for (int n = 0; n < 16; ++n) Aa[n] = -__expf(A_log[d * 16 + n]);
    float h[16];
    const float* h0p = &h0[(size_t)c * (DINNER * 16) + d * 16];
    #pragma unroll
    for (int n = 0; n < 16; n += 4) {
        float4 v = *(const float4*)&h0p[n];
        h[n] = v.x; h[n + 1] = v.y; h[n + 2] = v.z; h[n + 3] = v.w;
    }
    const float Dd = Dp[d];
    for (int t = 0; t < TCH; ++t) {
        const float dl = delta[(size_t)(t0 + t) * DINNER + d];
        const float u  = xs[(size_t)(t0 + t) * DINNER + d];
        const float du = dl * u;
        float y = 0.f;
        #pragma unroll
        for (int n = 0; n < 16; ++n) {
            h[n] = fmaf(h[n], __expf(dl * Aa[n]), du * BC[t][n]);
            y = fmaf(h[n], BC[t][16 + n], y);
        }
        const float res = xz[(size_t)(t0 + t) * N_XZ + DINNER + d];
        yg_bf[(size_t)(t0 + t) * DINNER + d] = f2bf((y + u * Dd) * silu_f(res));
    }
}

extern "C" void kernel_launch(void* const* d_in, const int* in_sizes, int n_in,
                              void* d_out, int out_size, void* d_ws, size_t ws_size,
                              hipStream_t stream) {
    const float* x     = (const float*)d_in[0];
    const float* wn    = (const float*)d_in[1];
    const float* W_in  = (const float*)d_in[2];
    const float* cw    = (const float*)d_in[3];
    const float* cb    = (const float*)d_in[4];
    const float* W_xp  = (const float*)d_in[5];
    const float* W_dt  = (const float*)d_in[6];
    const float* b_dt  = (const float*)d_in[7];
    const float* A_log = (const float*)d_in[8];
    const float* Dp    = (const float*)d_in[9];
    const float* W_out = (const float*)d_in[10];
    float* out = (float*)d_out;

    float* ws = (float*)d_ws;
    float*          xz    = ws;                                   //  8,388,608 f
    float*          xs    = xz + 8388608;                         //  4,194,304 f
    float*          delta = xs + 4194304;                         //  4,194,304 f
    float*          xdbc  = delta + 4194304;                      //    163,840 f
    float*          part  = xdbc + 163840;                        //  2,621,440 f (split-K partials)
    // part region is dead after reduce_sk -> reuse for scan scratch:
    float*          S     = part;                                 //  1,048,576 f
    float*          sumdl = S + 1048576;                          //     65,536 f
    float*          h0    = sumdl + 65536;                        //  1,048,576 f
    unsigned short* xn_bf = (unsigned short*)(part + 2621440);    //  2,097,152 sh
    // xn_bf dead after xz GEMM -> reuse for small bf16 buffers:
    unsigned short* BTxp  = xn_bf;                                //    655,360 sh (160 x 4096)
    unsigned short* BTdt  = BTxp + 655360;                        //    524,288 sh (4096 x 128)
    unsigned short* xdbc_dt = BTdt + 524288;                      //    131,072 sh (1024 x 128)
    unsigned short* xs_bf = xn_bf + 2097152;                      //  4,194,304 sh
    unsigned short* yg_bf = xs_bf + 4194304;                      //  4,194,304 sh
    unsigned short* BT    = yg_bf + 4194304;                      // 16,777,216 sh (big-W transpose, reused)
    // total ws use: ~133 MB

    // 1. W_in (2048x8192) -> BT bf16 (8192x2048)
    transpose_bf16_kernel<<<dim3(N_XZ / 32, DMODEL / 32), 256, 0, stream>>>(W_in, BT, DMODEL, N_XZ);
    // 2. RMSNorm -> bf16
    rmsnorm_kernel<<<L_SEQ, 256, 0, stream>>>(x, wn, xn_bf);
    // 3. xz = xn @ W_in  (MFMA, 1024x8192, K=2048)
    gemm_mfma_kernel<128, 128, 0><<<dim3(N_XZ / 128, L_SEQ / 128), 256, 0, stream>>>(
        xn_bf, BT, xz, DMODEL, DMODEL, N_XZ, N_XZ, nullptr, nullptr);
    // 4. conv + silu -> xs fp32 + bf16
    conv_silu_kernel<<<(L_SEQ * DINNER) / 256, 256, 0, stream>>>(xz, cw, cb, xs, xs_bf);
    // 5. W_xp (4096x160) -> BTxp (160x4096); W_dt (128x4096) -> BTdt (4096x128)
    transpose_bf16_kernel<<<dim3(N_XP / 32, DINNER / 32), 256, 0, stream>>>(W_xp, BTxp, DINNER, N_XP);
    transpose_bf16_kernel<<<dim3(DINNER / 32, DTRANK / 32), 256, 0, stream>>>(W_dt, BTdt, DTRANK, DINNER);
    // 6. xdbc = xs @ W_xp  (MFMA split-K x16, partials fp32)
    gemm_mfma_kernel<128, 64, 0><<<dim3(3, L_SEQ / 128, SK_XP), 256, 0, stream>>>(
        xs_bf, BTxp, part, DINNER, DINNER / SK_XP, N_XP, N_XP, nullptr, nullptr);
    reduce_sk_kernel<<<(L_SEQ * N_XP) / 256, 256, 0, stream>>>(part, xdbc, xdbc_dt);
    // 7. delta = softplus(xdbc[:, :128] @ W_dt + b_dt)  (MFMA, 1024x4096, K=128)
    gemm_mfma_kernel<128, 128, 1><<<dim3(DINNER / 128, L_SEQ / 128), 256, 0, stream>>>(
        xdbc_dt, BTdt, delta, DTRANK, DTRANK, DINNER, DINNER, b_dt, nullptr);
    // 8. selective scan (3 passes) + gate -> yg bf16
    scan_pass1<<<dim3(DINNER / 256, NCHUNK), 256, 0, stream>>>(delta, xs, xdbc, A_log, S, sumdl);
    scan_pass2<<<(DINNER * 16) / 256, 256, 0, stream>>>(S, sumdl, A_log, h0);
    scan_pass3<<<dim3(DINNER / 256, NCHUNK), 256, 0, stream>>>(delta, xs, xdbc, xz, A_log, Dp, h0, yg_bf);
    // 9. W_out (4096x2048) -> BT bf16 (2048x4096)
    transpose_bf16_kernel<<<dim3(DMODEL / 32, DINNER / 32), 256, 0, stream>>>(W_out, BT, DINNER, DMODEL);
    // 10. out = yg @ W_out + x  (MFMA, 1024x2048, K=4096)
    gemm_mfma_kernel<64, 128, 2><<<dim3(DMODEL / 128, L_SEQ / 64), 256, 0, stream>>>(
        yg_bf, BT, out, DINNER, DINNER, DMODEL, DMODEL, nullptr, x);
}

// Round 4
// 356.870 us; speedup vs baseline: 6.2921x; 1.1798x over previous
//
#include <hip/hip_runtime.h>
#include <math.h>

#define L_SEQ   1024
#define DMODEL  2048
#define DINNER  4096
#define DSTATE  16
#define DTRANK  128
#define N_XZ    (2 * DINNER)            // 8192
#define N_XP    (DTRANK + 2 * DSTATE)   // 160
#define EPS_F   1e-5f
#define NCHUNK  32
#define TCH     32
#define SK_XP   16                      // split-K factor for xdbc GEMM

using bf16x8 = __attribute__((ext_vector_type(8))) short;
using f32x4  = __attribute__((ext_vector_type(4))) float;

__device__ __forceinline__ float silu_f(float v) {
    return v * (1.0f / (1.0f + __expf(-v)));
}
__device__ __forceinline__ float softplus_f(float v) {
    return (v > 15.0f) ? v : log1pf(__expf(v));
}
__device__ __forceinline__ unsigned short f2bf(float f) {
    unsigned b = __float_as_uint(f);
    return (unsigned short)((b + 0x7FFFu + ((b >> 16) & 1u)) >> 16);
}

#define GLOAD_LDS(gp, lp) \
    __builtin_amdgcn_global_load_lds((const __attribute__((address_space(1))) void*)(gp), \
                                     (__attribute__((address_space(3))) void*)(lp), 16, 0, 0)

// ---------------- fp32 W (K x N) -> bf16 W^T (N x K), 32(n) x 64(k) tile ----------------
// Writes are ushort8 (16 B/lane, 128 B per 8-lane n-row segment).
__global__ __launch_bounds__(256) void transpose_bf16_kernel(const float* __restrict__ W,
                                                             unsigned short* __restrict__ BT,
                                                             int K, int N) {
    __shared__ unsigned short Tl[32][72];   // row stride 144 B (16-B aligned)
    const int k0 = blockIdx.y * 64, n0 = blockIdx.x * 32;
    const int kr = threadIdx.x >> 3;
    const int nc = (threadIdx.x & 7) * 4;
    float4 v0 = *(const float4*)&W[(size_t)(k0 + kr) * N + n0 + nc];
    float4 v1 = *(const float4*)&W[(size_t)(k0 + kr + 32) * N + n0 + nc];
    Tl[nc + 0][kr] = f2bf(v0.x); Tl[nc + 1][kr] = f2bf(v0.y);
    Tl[nc + 2][kr] = f2bf(v0.z); Tl[nc + 3][kr] = f2bf(v0.w);
    Tl[nc + 0][kr + 32] = f2bf(v1.x); Tl[nc + 1][kr + 32] = f2bf(v1.y);
    Tl[nc + 2][kr + 32] = f2bf(v1.z); Tl[nc + 3][kr + 32] = f2bf(v1.w);
    __syncthreads();
    const int n = threadIdx.x >> 3;
    const int k8 = (threadIdx.x & 7) * 8;
    *(bf16x8*)&BT[(size_t)(n0 + n) * K + k0 + k8] = *(const bf16x8*)&Tl[n][k8];
}

// ---------------- RMSNorm -> bf16 ----------------
__global__ __launch_bounds__(256) void rmsnorm_kernel(const float* __restrict__ x,
                                                      const float* __restrict__ w,
                                                      unsigned short* __restrict__ xn) {
    const int row = blockIdx.x;
    const float4* xr = (const float4*)(x + (size_t)row * DMODEL);
    float ss = 0.f;
    float4 v0 = xr[threadIdx.x];
    float4 v1 = xr[threadIdx.x + 256];
    ss += v0.x*v0.x + v0.y*v0.y + v0.z*v0.z + v0.w*v0.w;
    ss += v1.x*v1.x + v1.y*v1.y + v1.z*v1.z + v1.w*v1.w;
    #pragma unroll
    for (int o = 32; o > 0; o >>= 1) ss += __shfl_down(ss, o);
    __shared__ float red[4];
    const int lane = threadIdx.x & 63, wv = threadIdx.x >> 6;
    if (lane == 0) red[wv] = ss;
    __syncthreads();
    if (threadIdx.x == 0) {
        float t = red[0] + red[1] + red[2] + red[3];
        red[0] = rsqrtf(t / (float)DMODEL + EPS_F);
    }
    __syncthreads();
    const float scale = red[0];
    const float4* wr = (const float4*)w;
    float4 w0 = wr[threadIdx.x];
    float4 w1 = wr[threadIdx.x + 256];
    ushort4 o0, o1;
    o0.x = f2bf(v0.x * scale * w0.x); o0.y = f2bf(v0.y * scale * w0.y);
    o0.z = f2bf(v0.z * scale * w0.z); o0.w = f2bf(v0.w * scale * w0.w);
    o1.x = f2bf(v1.x * scale * w1.x); o1.y = f2bf(v1.y * scale * w1.y);
    o1.z = f2bf(v1.z * scale * w1.z); o1.w = f2bf(v1.w * scale * w1.w);
    unsigned short* outr = xn + (size_t)row * DMODEL;
    *(ushort4*)&outr[threadIdx.x * 4] = o0;
    *(ushort4*)&outr[1024 + threadIdx.x * 4] = o1;
}

// ---------------- bf16 MFMA GEMM: C(MxN fp32) = A(MxK bf16) @ BT(NxK bf16)^T ----------------
// 4 waves 2x2; wave tile (BM/2 x BN/2). XOR-swizzled LDS chunk slots kill
// ds_read_b128 bank conflicts (slot = chunk ^ ((row>>1)&3)).
// MODE 0: plain (split-K partial via blockIdx.z)
// MODE 1: softplus(v + bias[col])    MODE 2: v + resid[row,col]
template <int BM, int BN, int MODE>
__global__ __launch_bounds__(256) void gemm_mfma_kernel(const unsigned short* __restrict__ A,
                                                        const unsigned short* __restrict__ BT,
                                                        float* __restrict__ C,
                                                        int K, int Kc, int ldc, int Ncols,
                                                        const float* __restrict__ bias,
                                                        const float* __restrict__ resid) {
    constexpr int MT = BM / 32;
    constexpr int NT = BN / 32;
    __shared__ __align__(16) unsigned short Al[BM * 32];
    __shared__ __align__(16) unsigned short Bl[BN * 32];
    const int tid = threadIdx.x;
    const int lane = tid & 63, wave = tid >> 6;
    const int wm = wave >> 1, wn = wave & 1;
    const int bm = blockIdx.y * BM, bn = blockIdx.x * BN;
    const size_t koff = (size_t)blockIdx.z * Kc;
    C += (size_t)blockIdx.z * (size_t)gridDim.y * BM * ldc;
    const int sr = lane >> 2;                              // staging row in 16-row group
    const int sk = (((lane & 3) ^ ((sr >> 1) & 3))) * 8;   // swizzled k-chunk to fetch
    const int fr = lane & 15;
    const int fq = lane >> 4;
    const int fsw = (fq ^ ((fr >> 1) & 3)) * 8;            // swizzled chunk slot to read

    f32x4 acc[MT][NT];
    #pragma unroll
    for (int i = 0; i < MT; ++i)
        #pragma unroll
        for (int j = 0; j < NT; ++j)
            acc[i][j] = (f32x4){0.f, 0.f, 0.f, 0.f};

    for (int k0 = 0; k0 < Kc; k0 += 32) {
        #pragma unroll
        for (int is = wave; is < BM / 16; is += 4)
            GLOAD_LDS(&A[(size_t)(bm + is * 16 + sr) * K + koff + k0 + sk], &Al[is * 512]);
        #pragma unroll
        for (int is = wave; is < BN / 16; is += 4)
            GLOAD_LDS(&BT[(size_t)(bn + is * 16 + sr) * K + koff + k0 + sk], &Bl[is * 512]);
        __syncthreads();
        bf16x8 af[MT], bfr[NT];
        #pragma unroll
        for (int i = 0; i < MT; ++i)
            af[i] = *(const bf16x8*)&Al[(wm * (BM / 2) + i * 16 + fr) * 32 + fsw];
        #pragma unroll
        for (int j = 0; j < NT; ++j)
            bfr[j] = *(const bf16x8*)&Bl[(wn * (BN / 2) + j * 16 + fr) * 32 + fsw];
        #pragma unroll
        for (int i = 0; i < MT; ++i)
            #pragma unroll
            for (int j = 0; j < NT; ++j)
                acc[i][j] = __builtin_amdgcn_mfma_f32_16x16x32_bf16(af[i], bfr[j], acc[i][j], 0, 0, 0);
        __syncthreads();
    }

    #pragma unroll
    for (int i = 0; i < MT; ++i) {
        const int row = bm + wm * (BM / 2) + i * 16 + fq * 4;
        #pragma unroll
        for (int j = 0; j < NT; ++j) {
            const int col = bn + wn * (BN / 2) + j * 16 + fr;
            if (col < Ncols) {
                #pragma unroll
                for (int r = 0; r < 4; ++r) {
                    float v = acc[i][j][r];
                    if (MODE == 1) v = softplus_f(v + bias[col]);
                    if (MODE == 2) v += resid[(size_t)(row + r) * ldc + col];
                    C[(size_t)(row + r) * ldc + col] = v;
                }
            }
        }
    }
}

// ---------------- Depthwise causal conv (k=4) + SiLU; fp32 + bf16 outputs ----------------
__global__ __launch_bounds__(256) void conv_silu_kernel(const float* __restrict__ xz,
                                                        const float* __restrict__ cw,
                                                        const float* __restrict__ cb,
                                                        float* __restrict__ xs,
                                                        unsigned short* __restrict__ xs_bf) {
    const int idx = blockIdx.x * 256 + threadIdx.x;
    const int t = idx >> 12;
    const int c = idx & (DINNER - 1);
    float acc = cb[c];
    #pragma unroll
    for (int k = 0; k < 4; ++k) {
        const int tt = t + k - 3;
        if (tt >= 0) acc = fmaf(xz[(size_t)tt * N_XZ + c], cw[k * DINNER + c], acc);
    }
    const float s = silu_f(acc);
    xs[idx] = s;
    xs_bf[idx] = f2bf(s);
}

// ---------------- reduce SK_XP split-K partials -> xdbc fp32 (+ bf16 dt cols) ----------------
__global__ __launch_bounds__(256) void reduce_sk_kernel(const float* __restrict__ part,
                                                        float* __restrict__ xdbc,
                                                        unsigned short* __restrict__ xdbc_dt) {
    const int i = blockIdx.x * 256 + threadIdx.x;     // row*160 + col
    float s = 0.f;
    #pragma unroll
    for (int c = 0; c < SK_XP; ++c) s += part[(size_t)c * (L_SEQ * N_XP) + i];
    xdbc[i] = s;
    const int col = i % N_XP;
    if (col < DTRANK) xdbc_dt[(i / N_XP) * DTRANK + col] = f2bf(s);
}

// ---------------- Selective scan, 3-pass chunked linear recurrence ----------------
__global__ __launch_bounds__(256) void scan_pass1(const float* __restrict__ delta,
                                                  const float* __restrict__ xs,
                                                  const float* __restrict__ xdbc,
                                                  const float* __restrict__ A_log,
                                                  float* __restrict__ S,
                                                  float* __restrict__ sumdl) {
    __shared__ float BC[TCH][32];
    const int c = blockIdx.y;
    const int d = blockIdx.x * 256 + threadIdx.x;
    const int t0 = c * TCH;
    {
        const int tt = threadIdx.x >> 3, q = threadIdx.x & 7;
        *(float4*)&BC[tt][q * 4] =
            *(const float4*)&xdbc[(size_t)(t0 + tt) * N_XP + DTRANK + q * 4];
    }
    __syncthreads();
    float Aa[16];
    #pragma unroll
    for (int n = 0; n < 16; ++n) Aa[n] = -__expf(A_log[d * 16 + n]);
    float h[16];
    #pragma unroll
    for (int n = 0; n < 16; ++n) h[n] = 0.f;
    float sd = 0.f;
    for (int t = 0; t < TCH; ++t) {
        const float dl = delta[(size_t)(t0 + t) * DINNER + d];
        const float u  = xs[(size_t)(t0 + t) * DINNER + d];
        sd += dl;
        const float du = dl * u;
        #pragma unroll
        for (int n = 0; n < 16; ++n)
            h[n] = fmaf(h[n], __expf(dl * Aa[n]), du * BC[t][n]);
    }
    float* Sp = &S[((size_t)c * DINNER + d) * 16];
    #pragma unroll
    for (int n = 0; n < 16; n += 4)
        *(float4*)&Sp[n] = make_float4(h[n], h[n + 1], h[n + 2], h[n + 3]);
    sumdl[c * DINNER + d] = sd;
}

__global__ __launch_bounds__(256) void scan_pass2(const float* __restrict__ S,
                                                  const float* __restrict__ sumdl,
                                                  const float* __restrict__ A_log,
                                                  float* __restrict__ h0) {
    const int i = blockIdx.x * 256 + threadIdx.x;   // d*16 + n
    const int dd = i >> 4;
    const float A = -__expf(A_log[i]);
    float h = 0.f;
    #pragma unroll
    for (int c = 0; c < NCHUNK; ++c) {
        h0[(size_t)c * (DINNER * 16) + i] = h;
        h = h * __expf(A * sumdl[c * DINNER + dd]) + S[(size_t)c * (DINNER * 16) + i];
    }
}

__global__ __launch_bounds__(256) void scan_pass3(const float* __restrict__ delta,
                                                  const float* __restrict__ xs,
                                                  const float* __restrict__ xdbc,
                                                  const float* __restrict__ xz,
                                                  const float* __restrict__ A_log,
                                                  const float* __restrict__ Dp,
                                                  const float* __restrict__ h0,
                                                  unsigned short* __restrict__ yg_bf) {
    __shared__ float BC[TCH][32];
    const int c = blockIdx.y;
    const int d = blockIdx.x * 256 + threadIdx.x;
    const int t0 = c * TCH;
    {
        const int tt = threadIdx.x >> 3, q = threadIdx.x & 7;
        *(float4*)&BC[tt][q * 4] =
            *(const float4*)&xdbc[(size_t)(t0 + tt) * N_XP + DTRANK + q * 4];
    }
    __syncthreads();
    float Aa[16];
    #pragma unroll
    for (int n = 0; n < 16; ++n) Aa[n] = -__expf(A_log[d * 16 + n]);
    float h[16];
    const float* h0p = &h0[(size_t)c * (DINNER * 16) + d * 16];
    #pragma unroll
    for (int n = 0; n < 16; n += 4) {
        float4 v = *(const float4*)&h0p[n];
        h[n] = v.x; h[n + 1] = v.y; h[n + 2] = v.z; h[n + 3] = v.w;
    }
    const float Dd = Dp[d];
    for (int t = 0; t < TCH; ++t) {
        const float dl = delta[(size_t)(t0 + t) * DINNER + d];
        const float u  = xs[(size_t)(t0 + t) * DINNER + d];
        const float du = dl * u;
        float y = 0.f;
        #pragma unroll
        for (int n = 0; n < 16; ++n) {
            h[n] = fmaf(h[n], __expf(dl * Aa[n]), du * BC[t][n]);
            y = fmaf(h[n], BC[t][16 + n], y);
        }
        const float res = xz[(size_t)(t0 + t) * N_XZ + DINNER + d];
        yg_bf[(size_t)(t0 + t) * DINNER + d] = f2bf((y + u * Dd) * silu_f(res));
    }
}

extern "C" void kernel_launch(void* const* d_in, const int* in_sizes, int n_in,
                              void* d_out, int out_size, void* d_ws, size_t ws_size,
                              hipStream_t stream) {
    const float* x     = (const float*)d_in[0];
    const float* wn    = (const float*)d_in[1];
    const float* W_in  = (const float*)d_in[2];
    const float* cw    = (const float*)d_in[3];
    const float* cb    = (const float*)d_in[4];
    const float* W_xp  = (const float*)d_in[5];
    const float* W_dt  = (const float*)d_in[6];
    const float* b_dt  = (const float*)d_in[7];
    const float* A_log = (const float*)d_in[8];
    const float* Dp    = (const float*)d_in[9];
    const float* W_out = (const float*)d_in[10];
    float* out = (float*)d_out;

    float* ws = (float*)d_ws;
    float*          xz    = ws;                                   //  8,388,608 f
    float*          xs    = xz + 8388608;                         //  4,194,304 f
    float*          delta = xs + 4194304;                         //  4,194,304 f
    float*          xdbc  = delta + 4194304;                      //    163,840 f
    float*          part  = xdbc + 163840;                        //  2,621,440 f (split-K partials)
    // part dead after reduce_sk -> S (2,097,152) + sumdl (131,072) fit inside:
    float*          S     = part;
    float*          sumdl = S + 2097152;
    float*          h0    = part + 2621440;                       //  2,097,152 f
    unsigned short* xn_bf = (unsigned short*)(h0 + 2097152);      //  2,097,152 sh
    // xn_bf dead after xz GEMM -> reuse for small bf16 buffers:
    unsigned short* BTxp  = xn_bf;                                //    655,360 sh (160 x 4096)
    unsigned short* BTdt  = BTxp + 655360;                        //    524,288 sh (4096 x 128)
    unsigned short* xdbc_dt = BTdt + 524288;                      //    131,072 sh (1024 x 128)
    unsigned short* xs_bf = xn_bf + 2097152;                      //  4,194,304 sh
    unsigned short* yg_bf = xs_bf + 4194304;                      //  4,194,304 sh
    unsigned short* BT    = yg_bf + 4194304;                      // 16,777,216 sh (big-W transpose, reused)
    // total ws use: ~135 MB

    // 1. W_in (2048x8192) -> BT bf16 (8192x2048)
    transpose_bf16_kernel<<<dim3(N_XZ / 32, DMODEL / 64), 256, 0, stream>>>(W_in, BT, DMODEL, N_XZ);
    // 2. RMSNorm -> bf16
    rmsnorm_kernel<<<L_SEQ, 256, 0, stream>>>(x, wn, xn_bf);
    // 3. xz = xn @ W_in  (MFMA, 1024x8192, K=2048; 1024 blocks = 4/CU)
    gemm_mfma_kernel<64, 128, 0><<<dim3(N_XZ / 128, L_SEQ / 64), 256, 0, stream>>>(
        xn_bf, BT, xz, DMODEL, DMODEL, N_XZ, N_XZ, nullptr, nullptr);
    // 4. conv + silu -> xs fp32 + bf16
    conv_silu_kernel<<<(L_SEQ * DINNER) / 256, 256, 0, stream>>>(xz, cw, cb, xs, xs_bf);
    // 5. W_xp (4096x160) -> BTxp (160x4096); W_dt (128x4096) -> BTdt (4096x128)
    transpose_bf16_kernel<<<dim3(N_XP / 32, DINNER / 64), 256, 0, stream>>>(W_xp, BTxp, DINNER, N_XP);
    transpose_bf16_kernel<<<dim3(DINNER / 32, DTRANK / 64), 256, 0, stream>>>(W_dt, BTdt, DTRANK, DINNER);
    // 6. xdbc = xs @ W_xp  (MFMA split-K x16, partials fp32)
    gemm_mfma_kernel<128, 64, 0><<<dim3(3, L_SEQ / 128, SK_XP), 256, 0, stream>>>(
        xs_bf, BTxp, part, DINNER, DINNER / SK_XP, N_XP, N_XP, nullptr, nullptr);
    reduce_sk_kernel<<<(L_SEQ * N_XP) / 256, 256, 0, stream>>>(part, xdbc, xdbc_dt);
    // 7. delta = softplus(xdbc[:, :128] @ W_dt + b_dt)  (MFMA, 1024x4096, K=128; 1024 blocks)
    gemm_mfma_kernel<64, 64, 1><<<dim3(DINNER / 64, L_SEQ / 64), 256, 0, stream>>>(
        xdbc_dt, BTdt, delta, DTRANK, DTRANK, DINNER, DINNER, b_dt, nullptr);
    // 8. selective scan (3 passes, 32 chunks) + gate -> yg bf16
    scan_pass1<<<dim3(DINNER / 256, NCHUNK), 256, 0, stream>>>(delta, xs, xdbc, A_log, S, sumdl);
    scan_pass2<<<(DINNER * 16) / 256, 256, 0, stream>>>(S, sumdl, A_log, h0);
    scan_pass3<<<dim3(DINNER / 256, NCHUNK), 256, 0, stream>>>(delta, xs, xdbc, xz, A_log, Dp, h0, yg_bf);
    // 9. W_out (4096x2048) -> BT bf16 (2048x4096)
    transpose_bf16_kernel<<<dim3(DMODEL / 32, DINNER / 64), 256, 0, stream>>>(W_out, BT, DINNER, DMODEL);
    // 10. out = yg @ W_out + x  (MFMA, 1024x2048, K=4096; 512 blocks = 2/CU)
    gemm_mfma_kernel<64, 64, 2><<<dim3(DMODEL / 64, L_SEQ / 64), 256, 0, stream>>>(
        yg_bf, BT, out, DINNER, DINNER, DMODEL, DMODEL, nullptr, x);
}

// Round 5
// 339.955 us; speedup vs baseline: 6.6051x; 1.0498x over previous
//
#include <hip/hip_runtime.h>
#include <math.h>

#define L_SEQ   1024
#define DMODEL  2048
#define DINNER  4096
#define DSTATE  16
#define DTRANK  128
#define N_XZ    (2 * DINNER)            // 8192
#define N_XP    (DTRANK + 2 * DSTATE)   // 160
#define EPS_F   1e-5f
#define NCHUNK  32
#define TCH     32
#define SK_XP   16                      // split-K for xdbc GEMM
#define SK_OUT  2                       // split-K for out GEMM

using bf16x8 = __attribute__((ext_vector_type(8))) short;
using f32x4  = __attribute__((ext_vector_type(4))) float;

__device__ __forceinline__ float silu_f(float v) {
    return v * (1.0f / (1.0f + __expf(-v)));
}
__device__ __forceinline__ float softplus_f(float v) {
    return (v > 15.0f) ? v : log1pf(__expf(v));
}
__device__ __forceinline__ unsigned short f2bf(float f) {
    unsigned b = __float_as_uint(f);
    return (unsigned short)((b + 0x7FFFu + ((b >> 16) & 1u)) >> 16);
}
__device__ __forceinline__ float bf2f(unsigned short u) {
    return __uint_as_float((unsigned)u << 16);
}

#define GLOAD_LDS(gp, lp) \
    __builtin_amdgcn_global_load_lds((const __attribute__((address_space(1))) void*)(gp), \
                                     (__attribute__((address_space(3))) void*)(lp), 16, 0, 0)

// ================= mega-prep: all weight transposes + RMSNorm, one launch =================
// Transpose tile: 32(n) x 64(k); fp32 K x N -> bf16 N x K.
__device__ __forceinline__ void transpose_body(const float* __restrict__ W,
                                               unsigned short* __restrict__ BT,
                                               int K, int N, int bx, int by,
                                               unsigned short (*Tl)[72]) {
    const int k0 = by * 64, n0 = bx * 32;
    const int kr = threadIdx.x >> 3;
    const int nc = (threadIdx.x & 7) * 4;
    float4 v0 = *(const float4*)&W[(size_t)(k0 + kr) * N + n0 + nc];
    float4 v1 = *(const float4*)&W[(size_t)(k0 + kr + 32) * N + n0 + nc];
    Tl[nc + 0][kr] = f2bf(v0.x); Tl[nc + 1][kr] = f2bf(v0.y);
    Tl[nc + 2][kr] = f2bf(v0.z); Tl[nc + 3][kr] = f2bf(v0.w);
    Tl[nc + 0][kr + 32] = f2bf(v1.x); Tl[nc + 1][kr + 32] = f2bf(v1.y);
    Tl[nc + 2][kr + 32] = f2bf(v1.z); Tl[nc + 3][kr + 32] = f2bf(v1.w);
    __syncthreads();
    const int n = threadIdx.x >> 3;
    const int k8 = (threadIdx.x & 7) * 8;
    *(bf16x8*)&BT[(size_t)(n0 + n) * K + k0 + k8] = *(const bf16x8*)&Tl[n][k8];
}

__global__ __launch_bounds__(256) void prep_kernel(const float* __restrict__ W_in,
                                                   const float* __restrict__ W_xp,
                                                   const float* __restrict__ W_dt,
                                                   const float* __restrict__ W_out,
                                                   const float* __restrict__ x,
                                                   const float* __restrict__ wn,
                                                   unsigned short* __restrict__ BT_in,
                                                   unsigned short* __restrict__ BTxp,
                                                   unsigned short* __restrict__ BTdt,
                                                   unsigned short* __restrict__ BT_out,
                                                   unsigned short* __restrict__ xn_bf) {
    __shared__ unsigned short Tl[32][72];
    __shared__ float red[4];
    int b = blockIdx.x;
    if (b < 8192) {                       // W_in: K=2048, N=8192 -> (256 x 32)
        transpose_body(W_in, BT_in, DMODEL, N_XZ, b % 256, b / 256, Tl);
    } else if (b < 12288) {               // W_out: K=4096, N=2048 -> (64 x 64)
        b -= 8192;
        transpose_body(W_out, BT_out, DINNER, DMODEL, b % 64, b / 64, Tl);
    } else if (b < 12608) {               // W_xp: K=4096, N=160 -> (5 x 64)
        b -= 12288;
        transpose_body(W_xp, BTxp, DINNER, N_XP, b % 5, b / 5, Tl);
    } else if (b < 12864) {               // W_dt: K=128, N=4096 -> (128 x 2)
        b -= 12608;
        transpose_body(W_dt, BTdt, DTRANK, DINNER, b % 128, b / 128, Tl);
    } else {                              // RMSNorm rows 0..1023
        const int row = b - 12864;
        const float4* xr = (const float4*)(x + (size_t)row * DMODEL);
        float ss = 0.f;
        float4 v0 = xr[threadIdx.x];
        float4 v1 = xr[threadIdx.x + 256];
        ss += v0.x*v0.x + v0.y*v0.y + v0.z*v0.z + v0.w*v0.w;
        ss += v1.x*v1.x + v1.y*v1.y + v1.z*v1.z + v1.w*v1.w;
        #pragma unroll
        for (int o = 32; o > 0; o >>= 1) ss += __shfl_down(ss, o);
        const int lane = threadIdx.x & 63, wv = threadIdx.x >> 6;
        if (lane == 0) red[wv] = ss;
        __syncthreads();
        if (threadIdx.x == 0) {
            float t = red[0] + red[1] + red[2] + red[3];
            red[0] = rsqrtf(t / (float)DMODEL + EPS_F);
        }
        __syncthreads();
        const float scale = red[0];
        const float4* wr = (const float4*)wn;
        float4 w0 = wr[threadIdx.x];
        float4 w1 = wr[threadIdx.x + 256];
        ushort4 o0, o1;
        o0.x = f2bf(v0.x * scale * w0.x); o0.y = f2bf(v0.y * scale * w0.y);
        o0.z = f2bf(v0.z * scale * w0.z); o0.w = f2bf(v0.w * scale * w0.w);
        o1.x = f2bf(v1.x * scale * w1.x); o1.y = f2bf(v1.y * scale * w1.y);
        o1.z = f2bf(v1.z * scale * w1.z); o1.w = f2bf(v1.w * scale * w1.w);
        unsigned short* outr = xn_bf + (size_t)row * DMODEL;
        *(ushort4*)&outr[threadIdx.x * 4] = o0;
        *(ushort4*)&outr[1024 + threadIdx.x * 4] = o1;
    }
}

// ================= bf16 MFMA GEMM =================
// C(MxN) = A(MxK bf16) @ BT(NxK bf16)^T. 4 waves 2x2, XOR-swizzled LDS (0 conflicts).
// OUTM 0: bf16 plain   OUTM 1: bf16 softplus(v+bias[col])   OUTM 2: fp32 plain (split-K partials)
template <int BM, int BN, int OUTM>
__global__ __launch_bounds__(256) void gemm_mfma_kernel(const unsigned short* __restrict__ A,
                                                        const unsigned short* __restrict__ BT,
                                                        void* __restrict__ Cv,
                                                        int K, int Kc, int ldc, int Ncols,
                                                        const float* __restrict__ bias) {
    constexpr int MT = BM / 32;
    constexpr int NT = BN / 32;
    __shared__ __align__(16) unsigned short Al[BM * 32];
    __shared__ __align__(16) unsigned short Bl[BN * 32];
    const int tid = threadIdx.x;
    const int lane = tid & 63, wave = tid >> 6;
    const int wm = wave >> 1, wn = wave & 1;
    const int bm = blockIdx.y * BM, bn = blockIdx.x * BN;
    const size_t koff = (size_t)blockIdx.z * Kc;
    const size_t zCoff = (size_t)blockIdx.z * (size_t)gridDim.y * BM * ldc;
    const int sr = lane >> 2;
    const int sk = (((lane & 3) ^ ((sr >> 1) & 3))) * 8;
    const int fr = lane & 15;
    const int fq = lane >> 4;
    const int fsw = (fq ^ ((fr >> 1) & 3)) * 8;

    f32x4 acc[MT][NT];
    #pragma unroll
    for (int i = 0; i < MT; ++i)
        #pragma unroll
        for (int j = 0; j < NT; ++j)
            acc[i][j] = (f32x4){0.f, 0.f, 0.f, 0.f};

    for (int k0 = 0; k0 < Kc; k0 += 32) {
        #pragma unroll
        for (int is = wave; is < BM / 16; is += 4)
            GLOAD_LDS(&A[(size_t)(bm + is * 16 + sr) * K + koff + k0 + sk], &Al[is * 512]);
        #pragma unroll
        for (int is = wave; is < BN / 16; is += 4)
            GLOAD_LDS(&BT[(size_t)(bn + is * 16 + sr) * K + koff + k0 + sk], &Bl[is * 512]);
        __syncthreads();
        bf16x8 af[MT], bfr[NT];
        #pragma unroll
        for (int i = 0; i < MT; ++i)
            af[i] = *(const bf16x8*)&Al[(wm * (BM / 2) + i * 16 + fr) * 32 + fsw];
        #pragma unroll
        for (int j = 0; j < NT; ++j)
            bfr[j] = *(const bf16x8*)&Bl[(wn * (BN / 2) + j * 16 + fr) * 32 + fsw];
        #pragma unroll
        for (int i = 0; i < MT; ++i)
            #pragma unroll
            for (int j = 0; j < NT; ++j)
                acc[i][j] = __builtin_amdgcn_mfma_f32_16x16x32_bf16(af[i], bfr[j], acc[i][j], 0, 0, 0);
        __syncthreads();
    }

    #pragma unroll
    for (int i = 0; i < MT; ++i) {
        const int row = bm + wm * (BM / 2) + i * 16 + fq * 4;
        #pragma unroll
        for (int j = 0; j < NT; ++j) {
            const int col = bn + wn * (BN / 2) + j * 16 + fr;
            if (col < Ncols) {
                #pragma unroll
                for (int r = 0; r < 4; ++r) {
                    float v = acc[i][j][r];
                    if (OUTM == 0) {
                        ((unsigned short*)Cv)[(size_t)(row + r) * ldc + col] = f2bf(v);
                    } else if (OUTM == 1) {
                        ((unsigned short*)Cv)[(size_t)(row + r) * ldc + col] =
                            f2bf(softplus_f(v + bias[col]));
                    } else {
                        ((float*)Cv + zCoff)[(size_t)(row + r) * ldc + col] = v;
                    }
                }
            }
        }
    }
}

// ================= Depthwise causal conv (k=4) + SiLU, bf16 in/out =================
__global__ __launch_bounds__(256) void conv_silu_kernel(const unsigned short* __restrict__ xz_bf,
                                                        const float* __restrict__ cw,
                                                        const float* __restrict__ cb,
                                                        unsigned short* __restrict__ xs_bf) {
    const int idx = blockIdx.x * 256 + threadIdx.x;
    const int t = idx >> 12;
    const int c = idx & (DINNER - 1);
    float acc = cb[c];
    #pragma unroll
    for (int k = 0; k < 4; ++k) {
        const int tt = t + k - 3;
        if (tt >= 0) acc = fmaf(bf2f(xz_bf[(size_t)tt * N_XZ + c]), cw[k * DINNER + c], acc);
    }
    xs_bf[idx] = f2bf(silu_f(acc));
}

// ================= reduce SK_XP split-K partials -> xdbc fp32 (+ bf16 dt cols) =================
__global__ __launch_bounds__(256) void reduce_sk_kernel(const float* __restrict__ part,
                                                        float* __restrict__ xdbc,
                                                        unsigned short* __restrict__ xdbc_dt) {
    const int i = blockIdx.x * 256 + threadIdx.x;     // row*160 + col
    float s = 0.f;
    #pragma unroll
    for (int c = 0; c < SK_XP; ++c) s += part[(size_t)c * (L_SEQ * N_XP) + i];
    xdbc[i] = s;
    const int col = i % N_XP;
    if (col < DTRANK) xdbc_dt[(i / N_XP) * DTRANK + col] = f2bf(s);
}

// ================= reduce out-GEMM split-K partials + residual =================
__global__ __launch_bounds__(256) void reduce_out_kernel(const float* __restrict__ part,
                                                         const float* __restrict__ x,
                                                         float* __restrict__ out) {
    const int i = blockIdx.x * 256 + threadIdx.x;     // float4 index
    float4 a = ((const float4*)part)[i];
    float4 b = ((const float4*)(part + (size_t)L_SEQ * DMODEL))[i];
    float4 r = ((const float4*)x)[i];
    float4 o;
    o.x = a.x + b.x + r.x; o.y = a.y + b.y + r.y;
    o.z = a.z + b.z + r.z; o.w = a.w + b.w + r.w;
    ((float4*)out)[i] = o;
}

// ================= Selective scan, 3-pass chunked linear recurrence (bf16 inputs) ========
__global__ __launch_bounds__(256) void scan_pass1(const unsigned short* __restrict__ delta_bf,
                                                  const unsigned short* __restrict__ xs_bf,
                                                  const float* __restrict__ xdbc,
                                                  const float* __restrict__ A_log,
                                                  float* __restrict__ S,
                                                  float* __restrict__ sumdl) {
    __shared__ float BC[TCH][32];
    const int c = blockIdx.y;
    const int d = blockIdx.x * 256 + threadIdx.x;
    const int t0 = c * TCH;
    {
        const int tt = threadIdx.x >> 3, q = threadIdx.x & 7;
        *(float4*)&BC[tt][q * 4] =
            *(const float4*)&xdbc[(size_t)(t0 + tt) * N_XP + DTRANK + q * 4];
    }
    __syncthreads();
    float Aa[16];
    #pragma unroll
    for (int n = 0; n < 16; ++n) Aa[n] = -__expf(A_log[d * 16 + n]);
    float h[16];
    #pragma unroll
    for (int n = 0; n < 16; ++n) h[n] = 0.f;
    float sd = 0.f;
    for (int t = 0; t < TCH; ++t) {
        const float dl = bf2f(delta_bf[(size_t)(t0 + t) * DINNER + d]);
        const float u  = bf2f(xs_bf[(size_t)(t0 + t) * DINNER + d]);
        sd += dl;
        const float du = dl * u;
        #pragma unroll
        for (int n = 0; n < 16; ++n)
            h[n] = fmaf(h[n], __expf(dl * Aa[n]), du * BC[t][n]);
    }
    float* Sp = &S[((size_t)c * DINNER + d) * 16];
    #pragma unroll
    for (int n = 0; n < 16; n += 4)
        *(float4*)&Sp[n] = make_float4(h[n], h[n + 1], h[n + 2], h[n + 3]);
    sumdl[c * DINNER + d] = sd;
}

__global__ __launch_bounds__(256) void scan_pass2(const float* __restrict__ S,
                                                  const float* __restrict__ sumdl,
                                                  const float* __restrict__ A_log,
                                                  float* __restrict__ h0) {
    const int i = blockIdx.x * 256 + threadIdx.x;   // d*16 + n
    const int dd = i >> 4;
    const float A = -__expf(A_log[i]);
    float h = 0.f;
    #pragma unroll
    for (int c = 0; c < NCHUNK; ++c) {
        h0[(size_t)c * (DINNER * 16) + i] = h;
        h = h * __expf(A * sumdl[c * DINNER + dd]) + S[(size_t)c * (DINNER * 16) + i];
    }
}

__global__ __launch_bounds__(256) void scan_pass3(const unsigned short* __restrict__ delta_bf,
                                                  const unsigned short* __restrict__ xs_bf,
                                                  const float* __restrict__ xdbc,
                                                  const unsigned short* __restrict__ xz_bf,
                                                  const float* __restrict__ A_log,
                                                  const float* __restrict__ Dp,
                                                  const float* __restrict__ h0,
                                                  unsigned short* __restrict__ yg_bf) {
    __shared__ float BC[TCH][32];
    const int c = blockIdx.y;
    const int d = blockIdx.x * 256 + threadIdx.x;
    const int t0 = c * TCH;
    {
        const int tt = threadIdx.x >> 3, q = threadIdx.x & 7;
        *(float4*)&BC[tt][q * 4] =
            *(const float4*)&xdbc[(size_t)(t0 + tt) * N_XP + DTRANK + q * 4];
    }
    __syncthreads();
    float Aa[16];
    #pragma unroll
    for (int n = 0; n < 16; ++n) Aa[n] = -__expf(A_log[d * 16 + n]);
    float h[16];
    const float* h0p = &h0[(size_t)c * (DINNER * 16) + d * 16];
    #pragma unroll
    for (int n = 0; n < 16; n += 4) {
        float4 v = *(const float4*)&h0p[n];
        h[n] = v.x; h[n + 1] = v.y; h[n + 2] = v.z; h[n + 3] = v.w;
    }
    const float Dd = Dp[d];
    for (int t = 0; t < TCH; ++t) {
        const float dl = bf2f(delta_bf[(size_t)(t0 + t) * DINNER + d]);
        const float u  = bf2f(xs_bf[(size_t)(t0 + t) * DINNER + d]);
        const float du = dl * u;
        float y = 0.f;
        #pragma unroll
        for (int n = 0; n < 16; ++n) {
            h[n] = fmaf(h[n], __expf(dl * Aa[n]), du * BC[t][n]);
            y = fmaf(h[n], BC[t][16 + n], y);
        }
        const float res = bf2f(xz_bf[(size_t)(t0 + t) * N_XZ + DINNER + d]);
        yg_bf[(size_t)(t0 + t) * DINNER + d] = f2bf((y + u * Dd) * silu_f(res));
    }
}

extern "C" void kernel_launch(void* const* d_in, const int* in_sizes, int n_in,
                              void* d_out, int out_size, void* d_ws, size_t ws_size,
                              hipStream_t stream) {
    const float* x     = (const float*)d_in[0];
    const float* wn    = (const float*)d_in[1];
    const float* W_in  = (const float*)d_in[2];
    const float* cw    = (const float*)d_in[3];
    const float* cb    = (const float*)d_in[4];
    const float* W_xp  = (const float*)d_in[5];
    const float* W_dt  = (const float*)d_in[6];
    const float* b_dt  = (const float*)d_in[7];
    const float* A_log = (const float*)d_in[8];
    const float* Dp    = (const float*)d_in[9];
    const float* W_out = (const float*)d_in[10];
    float* out = (float*)d_out;

    float* ws = (float*)d_ws;                                     // offsets in floats
    unsigned short* xz_bf    = (unsigned short*)ws;               // 8,388,608 sh (4,194,304 f)
    unsigned short* xs_bf    = (unsigned short*)(ws + 4194304);   // 4,194,304 sh
    unsigned short* yg_bf    = (unsigned short*)(ws + 6291456);   // 4,194,304 sh
    unsigned short* delta_bf = (unsigned short*)(ws + 8388608);   // 4,194,304 sh
    float*          part     = ws + 10485760;                     // 2,621,440 f (xdbc split-K)
    float*          S        = part;                              // alias (part dead after reduce_sk)
    float*          sumdl    = S + 2097152;                       //   131,072 f
    float*          h0       = ws + 13107200;                     // 2,097,152 f
    float*          xdbc     = ws + 15204352;                     //   163,840 f
    unsigned short* xn_bf    = (unsigned short*)(ws + 15368192);  // 2,097,152 sh
    unsigned short* BTxp     = (unsigned short*)(ws + 16416768);  //   655,360 sh
    unsigned short* BTdt     = (unsigned short*)(ws + 16744448);  //   524,288 sh
    unsigned short* xdbc_dt  = (unsigned short*)(ws + 17006592);  //   131,072 sh
    unsigned short* BT_in    = (unsigned short*)(ws + 17072128);  // 16,777,216 sh
    unsigned short* BT_out   = (unsigned short*)(ws + 25460736);  //  8,388,608 sh
    // out-GEMM split-K partials alias delta_bf + part (both dead by then):
    float*          part_out = ws + 8388608;                      // 4,194,304 f
    // total: 29,655,040 f = 118.6 MB

    // 1. mega-prep: 4 transposes + RMSNorm (13,888 blocks, one launch)
    prep_kernel<<<13888, 256, 0, stream>>>(W_in, W_xp, W_dt, W_out, x, wn,
                                           BT_in, BTxp, BTdt, BT_out, xn_bf);
    // 2. xz = xn @ W_in -> bf16  (128x128 tile, 512 blocks)
    gemm_mfma_kernel<128, 128, 0><<<dim3(N_XZ / 128, L_SEQ / 128), 256, 0, stream>>>(
        xn_bf, BT_in, xz_bf, DMODEL, DMODEL, N_XZ, N_XZ, nullptr);
    // 3. conv + silu -> xs bf16
    conv_silu_kernel<<<(L_SEQ * DINNER) / 256, 256, 0, stream>>>(xz_bf, cw, cb, xs_bf);
    // 4. xdbc = xs @ W_xp  (split-K x16, fp32 partials)
    gemm_mfma_kernel<128, 64, 2><<<dim3(3, L_SEQ / 128, SK_XP), 256, 0, stream>>>(
        xs_bf, BTxp, part, DINNER, DINNER / SK_XP, N_XP, N_XP, nullptr);
    reduce_sk_kernel<<<(L_SEQ * N_XP) / 256, 256, 0, stream>>>(part, xdbc, xdbc_dt);
    // 5. delta = softplus(xdbc_dt @ W_dt + b_dt) -> bf16  (1024 blocks)
    gemm_mfma_kernel<64, 64, 1><<<dim3(DINNER / 64, L_SEQ / 64), 256, 0, stream>>>(
        xdbc_dt, BTdt, delta_bf, DTRANK, DTRANK, DINNER, DINNER, b_dt);
    // 6. selective scan (3 passes, 32 chunks) + gate -> yg bf16
    scan_pass1<<<dim3(DINNER / 256, NCHUNK), 256, 0, stream>>>(delta_bf, xs_bf, xdbc, A_log, S, sumdl);
    scan_pass2<<<(DINNER * 16) / 256, 256, 0, stream>>>(S, sumdl, A_log, h0);
    scan_pass3<<<dim3(DINNER / 256, NCHUNK), 256, 0, stream>>>(delta_bf, xs_bf, xdbc, xz_bf,
                                                               A_log, Dp, h0, yg_bf);
    // 7. out = yg @ W_out + x  (split-K x2 fp32 partials, 1024 blocks; then reduce+resid)
    gemm_mfma_kernel<64, 64, 2><<<dim3(DMODEL / 64, L_SEQ / 64, SK_OUT), 256, 0, stream>>>(
        yg_bf, BT_out, part_out, DINNER, DINNER / SK_OUT, DMODEL, DMODEL, nullptr);
    reduce_out_kernel<<<(L_SEQ * DMODEL / 4) / 256, 256, 0, stream>>>(part_out, x, out);
}

// Round 7
// 336.873 us; speedup vs baseline: 6.6656x; 1.0091x over previous
//
#include <hip/hip_runtime.h>
#include <math.h>

#define L_SEQ   1024
#define DMODEL  2048
#define DINNER  4096
#define DSTATE  16
#define DTRANK  128
#define N_XZ    (2 * DINNER)            // 8192
#define N_XP    (DTRANK + 2 * DSTATE)   // 160
#define EPS_F   1e-5f
#define NCHUNK  32
#define TCH     32
#define SK_XP   16                      // split-K for xdbc GEMM

using bf16x8 = __attribute__((ext_vector_type(8))) short;
using f32x4  = __attribute__((ext_vector_type(4))) float;

__device__ __forceinline__ float silu_f(float v) {
    return v * (1.0f / (1.0f + __expf(-v)));
}
__device__ __forceinline__ float softplus_f(float v) {
    return (v > 15.0f) ? v : log1pf(__expf(v));
}
__device__ __forceinline__ unsigned short f2bf(float f) {
    unsigned b = __float_as_uint(f);
    return (unsigned short)((b + 0x7FFFu + ((b >> 16) & 1u)) >> 16);
}
__device__ __forceinline__ float bf2f(unsigned short u) {
    return __uint_as_float((unsigned)u << 16);
}

#define GLOAD_LDS(gp, lp) \
    __builtin_amdgcn_global_load_lds((const __attribute__((address_space(1))) void*)(gp), \
                                     (__attribute__((address_space(3))) void*)(lp), 16, 0, 0)

// ================= mega-prep: all weight transposes + RMSNorm, one launch =================
__device__ __forceinline__ void transpose_body(const float* __restrict__ W,
                                               unsigned short* __restrict__ BT,
                                               int K, int N, int bx, int by,
                                               unsigned short (*Tl)[72]) {
    const int k0 = by * 64, n0 = bx * 32;
    const int kr = threadIdx.x >> 3;
    const int nc = (threadIdx.x & 7) * 4;
    float4 v0 = *(const float4*)&W[(size_t)(k0 + kr) * N + n0 + nc];
    float4 v1 = *(const float4*)&W[(size_t)(k0 + kr + 32) * N + n0 + nc];
    Tl[nc + 0][kr] = f2bf(v0.x); Tl[nc + 1][kr] = f2bf(v0.y);
    Tl[nc + 2][kr] = f2bf(v0.z); Tl[nc + 3][kr] = f2bf(v0.w);
    Tl[nc + 0][kr + 32] = f2bf(v1.x); Tl[nc + 1][kr + 32] = f2bf(v1.y);
    Tl[nc + 2][kr + 32] = f2bf(v1.z); Tl[nc + 3][kr + 32] = f2bf(v1.w);
    __syncthreads();
    const int n = threadIdx.x >> 3;
    const int k8 = (threadIdx.x & 7) * 8;
    *(bf16x8*)&BT[(size_t)(n0 + n) * K + k0 + k8] = *(const bf16x8*)&Tl[n][k8];
}

__global__ __launch_bounds__(256) void prep_kernel(const float* __restrict__ W_in,
                                                   const float* __restrict__ W_xp,
                                                   const float* __restrict__ W_dt,
                                                   const float* __restrict__ W_out,
                                                   const float* __restrict__ x,
                                                   const float* __restrict__ wn,
                                                   unsigned short* __restrict__ BT_in,
                                                   unsigned short* __restrict__ BTxp,
                                                   unsigned short* __restrict__ BTdt,
                                                   unsigned short* __restrict__ BT_out,
                                                   unsigned short* __restrict__ xn_bf) {
    __shared__ unsigned short Tl[32][72];
    __shared__ float red[4];
    int b = blockIdx.x;
    if (b < 8192) {                       // W_in: K=2048, N=8192
        transpose_body(W_in, BT_in, DMODEL, N_XZ, b % 256, b / 256, Tl);
    } else if (b < 12288) {               // W_out: K=4096, N=2048
        b -= 8192;
        transpose_body(W_out, BT_out, DINNER, DMODEL, b % 64, b / 64, Tl);
    } else if (b < 12608) {               // W_xp: K=4096, N=160
        b -= 12288;
        transpose_body(W_xp, BTxp, DINNER, N_XP, b % 5, b / 5, Tl);
    } else if (b < 12864) {               // W_dt: K=128, N=4096
        b -= 12608;
        transpose_body(W_dt, BTdt, DTRANK, DINNER, b % 128, b / 128, Tl);
    } else {                              // RMSNorm rows 0..1023
        const int row = b - 12864;
        const float4* xr = (const float4*)(x + (size_t)row * DMODEL);
        float ss = 0.f;
        float4 v0 = xr[threadIdx.x];
        float4 v1 = xr[threadIdx.x + 256];
        ss += v0.x*v0.x + v0.y*v0.y + v0.z*v0.z + v0.w*v0.w;
        ss += v1.x*v1.x + v1.y*v1.y + v1.z*v1.z + v1.w*v1.w;
        #pragma unroll
        for (int o = 32; o > 0; o >>= 1) ss += __shfl_down(ss, o);
        const int lane = threadIdx.x & 63, wv = threadIdx.x >> 6;
        if (lane == 0) red[wv] = ss;
        __syncthreads();
        if (threadIdx.x == 0) {
            float t = red[0] + red[1] + red[2] + red[3];
            red[0] = rsqrtf(t / (float)DMODEL + EPS_F);
        }
        __syncthreads();
        const float scale = red[0];
        const float4* wr = (const float4*)wn;
        float4 w0 = wr[threadIdx.x];
        float4 w1 = wr[threadIdx.x + 256];
        ushort4 o0, o1;
        o0.x = f2bf(v0.x * scale * w0.x); o0.y = f2bf(v0.y * scale * w0.y);
        o0.z = f2bf(v0.z * scale * w0.z); o0.w = f2bf(v0.w * scale * w0.w);
        o1.x = f2bf(v1.x * scale * w1.x); o1.y = f2bf(v1.y * scale * w1.y);
        o1.z = f2bf(v1.z * scale * w1.z); o1.w = f2bf(v1.w * scale * w1.w);
        unsigned short* outr = xn_bf + (size_t)row * DMODEL;
        *(ushort4*)&outr[threadIdx.x * 4] = o0;
        *(ushort4*)&outr[1024 + threadIdx.x * 4] = o1;
    }
}

// ================= bf16 MFMA GEMM, BK = KC*32 per barrier pair =================
// C(MxN) = A(MxK bf16) @ BT(NxK bf16)^T. 4 waves 2x2, XOR-swizzled LDS planes.
// OUTM 0: bf16 plain                OUTM 1: bf16 softplus(v + aux[col])
// OUTM 2: fp32 split-K partial      OUTM 3: fp32 v + aux[row*ldc+col] (residual)
template <int BM, int BN, int KC, int OUTM>
__global__ __launch_bounds__(256) void gemm_mfma_kernel(const unsigned short* __restrict__ A,
                                                        const unsigned short* __restrict__ BT,
                                                        void* __restrict__ Cv,
                                                        int K, int Kc, int ldc, int Ncols,
                                                        const float* __restrict__ aux) {
    constexpr int MT = BM / 32;
    constexpr int NT = BN / 32;
    __shared__ __align__(16) unsigned short Al[KC * BM * 32];
    __shared__ __align__(16) unsigned short Bl[KC * BN * 32];
    const int tid = threadIdx.x;
    const int lane = tid & 63, wave = tid >> 6;
    const int wm = wave >> 1, wn = wave & 1;
    const int bm = blockIdx.y * BM, bn = blockIdx.x * BN;
    const size_t koff = (size_t)blockIdx.z * Kc;
    float* Cf = (float*)Cv;
    if (OUTM == 2) Cf += (size_t)blockIdx.z * (size_t)gridDim.y * BM * ldc;
    const int sr = lane >> 2;
    const int sk = (((lane & 3) ^ ((sr >> 1) & 3))) * 8;
    const int fr = lane & 15;
    const int fq = lane >> 4;
    const int fsw = (fq ^ ((fr >> 1) & 3)) * 8;

    f32x4 acc[MT][NT];
    #pragma unroll
    for (int i = 0; i < MT; ++i)
        #pragma unroll
        for (int j = 0; j < NT; ++j)
            acc[i][j] = (f32x4){0.f, 0.f, 0.f, 0.f};

    for (int k0 = 0; k0 < Kc; k0 += 32 * KC) {
        #pragma unroll
        for (int p = 0; p < KC; ++p) {
            #pragma unroll
            for (int is = wave; is < BM / 16; is += 4)
                GLOAD_LDS(&A[(size_t)(bm + is * 16 + sr) * K + koff + k0 + p * 32 + sk],
                          &Al[p * BM * 32 + is * 512]);
            #pragma unroll
            for (int is = wave; is < BN / 16; is += 4)
                GLOAD_LDS(&BT[(size_t)(bn + is * 16 + sr) * K + koff + k0 + p * 32 + sk],
                          &Bl[p * BN * 32 + is * 512]);
        }
        __syncthreads();
        #pragma unroll
        for (int p = 0; p < KC; ++p) {
            bf16x8 af[MT], bfr[NT];
            #pragma unroll
            for (int i = 0; i < MT; ++i)
                af[i] = *(const bf16x8*)&Al[p * BM * 32 + (wm * (BM / 2) + i * 16 + fr) * 32 + fsw];
            #pragma unroll
            for (int j = 0; j < NT; ++j)
                bfr[j] = *(const bf16x8*)&Bl[p * BN * 32 + (wn * (BN / 2) + j * 16 + fr) * 32 + fsw];
            #pragma unroll
            for (int i = 0; i < MT; ++i)
                #pragma unroll
                for (int j = 0; j < NT; ++j)
                    acc[i][j] = __builtin_amdgcn_mfma_f32_16x16x32_bf16(af[i], bfr[j], acc[i][j], 0, 0, 0);
        }
        __syncthreads();
    }

    #pragma unroll
    for (int i = 0; i < MT; ++i) {
        const int row = bm + wm * (BM / 2) + i * 16 + fq * 4;
        #pragma unroll
        for (int j = 0; j < NT; ++j) {
            const int col = bn + wn * (BN / 2) + j * 16 + fr;
            if (col < Ncols) {
                #pragma unroll
                for (int r = 0; r < 4; ++r) {
                    float v = acc[i][j][r];
                    if (OUTM == 0) {
                        ((unsigned short*)Cv)[(size_t)(row + r) * ldc + col] = f2bf(v);
                    } else if (OUTM == 1) {
                        ((unsigned short*)Cv)[(size_t)(row + r) * ldc + col] =
                            f2bf(softplus_f(v + aux[col]));
                    } else if (OUTM == 2) {
                        Cf[(size_t)(row + r) * ldc + col] = v;
                    } else {
                        Cf[(size_t)(row + r) * ldc + col] =
                            v + aux[(size_t)(row + r) * ldc + col];
                    }
                }
            }
        }
    }
}

// ================= Depthwise causal conv (k=4) + SiLU, bf16 in/out =================
__global__ __launch_bounds__(256) void conv_silu_kernel(const unsigned short* __restrict__ xz_bf,
                                                        const float* __restrict__ cw,
                                                        const float* __restrict__ cb,
                                                        unsigned short* __restrict__ xs_bf) {
    const int idx = blockIdx.x * 256 + threadIdx.x;
    const int t = idx >> 12;
    const int c = idx & (DINNER - 1);
    float acc = cb[c];
    #pragma unroll
    for (int k = 0; k < 4; ++k) {
        const int tt = t + k - 3;
        if (tt >= 0) acc = fmaf(bf2f(xz_bf[(size_t)tt * N_XZ + c]), cw[k * DINNER + c], acc);
    }
    xs_bf[idx] = f2bf(silu_f(acc));
}

// ================= reduce SK_XP split-K partials -> xdbc fp32 (+ bf16 dt cols) =================
__global__ __launch_bounds__(256) void reduce_sk_kernel(const float* __restrict__ part,
                                                        float* __restrict__ xdbc,
                                                        unsigned short* __restrict__ xdbc_dt) {
    const int i = blockIdx.x * 256 + threadIdx.x;     // row*160 + col
    float s = 0.f;
    #pragma unroll
    for (int c = 0; c < SK_XP; ++c) s += part[(size_t)c * (L_SEQ * N_XP) + i];
    xdbc[i] = s;
    const int col = i % N_XP;
    if (col < DTRANK) xdbc_dt[(i / N_XP) * DTRANK + col] = f2bf(s);
}

// ================= Selective scan, 3-pass chunked linear recurrence (bf16 inputs) ========
__global__ __launch_bounds__(256) void scan_pass1(const unsigned short* __restrict__ delta_bf,
                                                  const unsigned short* __restrict__ xs_bf,
                                                  const float* __restrict__ xdbc,
                                                  const float* __restrict__ A_log,
                                                  float* __restrict__ S,
                                                  float* __restrict__ sumdl) {
    __shared__ float BC[TCH][32];
    const int c = blockIdx.y;
    const int d = blockIdx.x * 256 + threadIdx.x;
    const int t0 = c * TCH;
    {
        const int tt = threadIdx.x >> 3, q = threadIdx.x & 7;
        *(float4*)&BC[tt][q * 4] =
            *(const float4*)&xdbc[(size_t)(t0 + tt) * N_XP + DTRANK + q * 4];
    }
    __syncthreads();
    float Aa[16];
    #pragma unroll
    for (int n = 0; n < 16; ++n) Aa[n] = -__expf(A_log[d * 16 + n]);
    float h[16];
    #pragma unroll
    for (int n = 0; n < 16; ++n) h[n] = 0.f;
    float sd = 0.f;
    for (int t = 0; t < TCH; ++t) {
        const float dl = bf2f(delta_bf[(size_t)(t0 + t) * DINNER + d]);
        const float u  = bf2f(xs_bf[(size_t)(t0 + t) * DINNER + d]);
        sd += dl;
        const float du = dl * u;
        #pragma unroll
        for (int n = 0; n < 16; ++n)
            h[n] = fmaf(h[n], __expf(dl * Aa[n]), du * BC[t][n]);
    }
    float* Sp = &S[((size_t)c * DINNER + d) * 16];
    #pragma unroll
    for (int n = 0; n < 16; n += 4)
        *(float4*)&Sp[n] = make_float4(h[n], h[n + 1], h[n + 2], h[n + 3]);
    sumdl[c * DINNER + d] = sd;
}

__global__ __launch_bounds__(256) void scan_pass2(const float* __restrict__ S,
                                                  const float* __restrict__ sumdl,
                                                  const float* __restrict__ A_log,
                                                  float* __restrict__ h0) {
    const int i = blockIdx.x * 256 + threadIdx.x;   // d*16 + n
    const int dd = i >> 4;
    const float A = -__expf(A_log[i]);
    float h = 0.f;
    #pragma unroll
    for (int c = 0; c < NCHUNK; ++c) {
        h0[(size_t)c * (DINNER * 16) + i] = h;
        h = h * __expf(A * sumdl[c * DINNER + dd]) + S[(size_t)c * (DINNER * 16) + i];
    }
}

__global__ __launch_bounds__(256) void scan_pass3(const unsigned short* __restrict__ delta_bf,
                                                  const unsigned short* __restrict__ xs_bf,
                                                  const float* __restrict__ xdbc,
                                                  const unsigned short* __restrict__ xz_bf,
                                                  const float* __restrict__ A_log,
                                                  const float* __restrict__ Dp,
                                                  const float* __restrict__ h0,
                                                  unsigned short* __restrict__ yg_bf) {
    __shared__ float BC[TCH][32];
    const int c = blockIdx.y;
    const int d = blockIdx.x * 256 + threadIdx.x;
    const int t0 = c * TCH;
    {
        const int tt = threadIdx.x >> 3, q = threadIdx.x & 7;
        *(float4*)&BC[tt][q * 4] =
            *(const float4*)&xdbc[(size_t)(t0 + tt) * N_XP + DTRANK + q * 4];
    }
    __syncthreads();
    float Aa[16];
    #pragma unroll
    for (int n = 0; n < 16; ++n) Aa[n] = -__expf(A_log[d * 16 + n]);
    float h[16];
    const float* h0p = &h0[(size_t)c * (DINNER * 16) + d * 16];
    #pragma unroll
    for (int n = 0; n < 16; n += 4) {
        float4 v = *(const float4*)&h0p[n];
        h[n] = v.x; h[n + 1] = v.y; h[n + 2] = v.z; h[n + 3] = v.w;
    }
    const float Dd = Dp[d];
    for (int t = 0; t < TCH; ++t) {
        const float dl = bf2f(delta_bf[(size_t)(t0 + t) * DINNER + d]);
        const float u  = bf2f(xs_bf[(size_t)(t0 + t) * DINNER + d]);
        const float du = dl * u;
        float y = 0.f;
        #pragma unroll
        for (int n = 0; n < 16; ++n) {
            h[n] = fmaf(h[n], __expf(dl * Aa[n]), du * BC[t][n]);
            y = fmaf(h[n], BC[t][16 + n], y);
        }
        const float res = bf2f(xz_bf[(size_t)(t0 + t) * N_XZ + DINNER + d]);
        yg_bf[(size_t)(t0 + t) * DINNER + d] = f2bf((y + u * Dd) * silu_f(res));
    }
}

extern "C" void kernel_launch(void* const* d_in, const int* in_sizes, int n_in,
                              void* d_out, int out_size, void* d_ws, size_t ws_size,
                              hipStream_t stream) {
    const float* x     = (const float*)d_in[0];
    const float* wn    = (const float*)d_in[1];
    const float* W_in  = (const float*)d_in[2];
    const float* cw    = (const float*)d_in[3];
    const float* cb    = (const float*)d_in[4];
    const float* W_xp  = (const float*)d_in[5];
    const float* W_dt  = (const float*)d_in[6];
    const float* b_dt  = (const float*)d_in[7];
    const float* A_log = (const float*)d_in[8];
    const float* Dp    = (const float*)d_in[9];
    const float* W_out = (const float*)d_in[10];
    float* out = (float*)d_out;

    float* ws = (float*)d_ws;                                     // offsets in floats
    unsigned short* xz_bf    = (unsigned short*)ws;               // [0, 4194304)
    unsigned short* xs_bf    = (unsigned short*)(ws + 4194304);   // [4194304, 6291456)
    unsigned short* yg_bf    = (unsigned short*)(ws + 6291456);   // [6291456, 8388608)
    unsigned short* delta_bf = (unsigned short*)(ws + 8388608);   // [8388608, 10485760)
    float*          part     = ws + 10485760;                     // 2,621,440 f
    float*          S        = ws + 13107200;                     // 2,097,152 f
    float*          sumdl    = ws + 15204352;                     //   131,072 f
    float*          h0       = ws + 15335424;                     // 2,097,152 f
    float*          xdbc     = ws + 17432576;                     //   163,840 f
    unsigned short* xn_bf    = (unsigned short*)(ws + 17596416);  // 2,097,152 sh
    unsigned short* BTxp     = (unsigned short*)(ws + 18644992);  //   655,360 sh
    unsigned short* BTdt     = (unsigned short*)(ws + 18972672);  //   524,288 sh
    unsigned short* xdbc_dt  = (unsigned short*)(ws + 19234816);  //   131,072 sh
    unsigned short* BT_in    = (unsigned short*)(ws + 19300352);  // 16,777,216 sh
    unsigned short* BT_out   = (unsigned short*)(ws + 27688960);  //  8,388,608 sh
    // total: 31,883,264 f = 127.5 MB

    // 1. mega-prep: 4 transposes + RMSNorm
    prep_kernel<<<13888, 256, 0, stream>>>(W_in, W_xp, W_dt, W_out, x, wn,
                                           BT_in, BTxp, BTdt, BT_out, xn_bf);
    // 2. xz = xn @ W_in -> bf16  (64x128 tile, 1024 blocks, BK=64)
    gemm_mfma_kernel<64, 128, 2, 0><<<dim3(N_XZ / 128, L_SEQ / 64), 256, 0, stream>>>(
        xn_bf, BT_in, xz_bf, DMODEL, DMODEL, N_XZ, N_XZ, nullptr);
    // 3. conv + silu -> xs bf16
    conv_silu_kernel<<<(L_SEQ * DINNER) / 256, 256, 0, stream>>>(xz_bf, cw, cb, xs_bf);
    // 4. xdbc = xs @ W_xp  (split-K x16, fp32 partials, 768 blocks, BK=64)
    gemm_mfma_kernel<64, 64, 2, 2><<<dim3(3, L_SEQ / 64, SK_XP), 256, 0, stream>>>(
        xs_bf, BTxp, part, DINNER, DINNER / SK_XP, N_XP, N_XP, nullptr);
    reduce_sk_kernel<<<(L_SEQ * N_XP) / 256, 256, 0, stream>>>(part, xdbc, xdbc_dt);
    // 5. delta = softplus(xdbc_dt @ W_dt + b_dt) -> bf16  (1024 blocks, BK=64)
    gemm_mfma_kernel<64, 64, 2, 1><<<dim3(DINNER / 64, L_SEQ / 64), 256, 0, stream>>>(
        xdbc_dt, BTdt, delta_bf, DTRANK, DTRANK, DINNER, DINNER, b_dt);
    // 6. selective scan (3 passes, 32 chunks) + gate -> yg bf16
    scan_pass1<<<dim3(DINNER / 256, NCHUNK), 256, 0, stream>>>(delta_bf, xs_bf, xdbc, A_log, S, sumdl);
    scan_pass2<<<(DINNER * 16) / 256, 256, 0, stream>>>(S, sumdl, A_log, h0);
    scan_pass3<<<dim3(DINNER / 256, NCHUNK), 256, 0, stream>>>(delta_bf, xs_bf, xdbc, xz_bf,
                                                               A_log, Dp, h0, yg_bf);
    // 7. out = yg @ W_out + x  (64x64 tile, 512 blocks, BK=64, fused residual)
    gemm_mfma_kernel<64, 64, 2, 3><<<dim3(DMODEL / 64, L_SEQ / 64), 256, 0, stream>>>(
        yg_bf, BT_out, out, DINNER, DINNER, DMODEL, DMODEL, x);
}